// Round 17
// baseline (139.833 us; speedup 1.0000x reference)
//
#include <hip/hip_runtime.h>
#include <cstdint>

__device__ __forceinline__ float leaky(float v) { return v >= 0.f ? v : 0.01f * v; }

// ================= Encoder level 0: staged conv5x5 + leaky + pool ====================
__global__ void __launch_bounds__(256) enc0_k(
    const float* __restrict__ x1, const float* __restrict__ x2,
    const float* __restrict__ w, const float* __restrict__ bias,
    float* __restrict__ c2, float* __restrict__ pout)
{
    constexpr int R = 256;
    __shared__ float ss[3 * 36 * 36];
    __shared__ float ws[4 * 3 * 25 + 4];
    int t = threadIdx.x;
    int n = blockIdx.y;
    int tileY = blockIdx.x >> 3, tileX = blockIdx.x & 7;
    int Y0 = 32 * tileY, X0 = 32 * tileX;
    const float* src = (n < 2) ? x1 + (size_t)n * 3 * R * R
                               : x2 + (size_t)(n - 2) * 3 * R * R;

    for (int i = t; i < 300; i += 256) ws[i] = w[i];
    if (t < 4) ws[300 + t] = bias[t];
    for (int ci = 0; ci < 3; ++ci) {
        const float* sp = src + (size_t)ci * R * R;
        for (int i = t; i < 1296; i += 256) {
            int r = i / 36, col = i - r * 36;
            int gy = Y0 - 2 + r, gx = X0 - 2 + col;
            float v = 0.f;
            if (gy >= 0 && gy < R && gx >= 0 && gx < R) v = sp[gy * R + gx];
            ss[ci * 1296 + i] = v;
        }
    }
    __syncthreads();

    int qx = t & 15, qy = t >> 4;
    float acc[4][2][2];
#pragma unroll
    for (int co = 0; co < 4; ++co) {
        float b0 = ws[300 + co];
        acc[co][0][0] = b0; acc[co][0][1] = b0; acc[co][1][0] = b0; acc[co][1][1] = b0;
    }
#pragma unroll
    for (int ci = 0; ci < 3; ++ci) {
        const float* sp = &ss[ci * 1296 + (2 * qy) * 36 + 2 * qx];
        float S[6][6];
#pragma unroll
        for (int i = 0; i < 6; ++i)
#pragma unroll
            for (int j = 0; j < 6; ++j) S[i][j] = sp[i * 36 + j];
#pragma unroll
        for (int co = 0; co < 4; ++co) {
#pragma unroll
            for (int dy = 0; dy < 5; ++dy) {
#pragma unroll
                for (int dx = 0; dx < 5; ++dx) {
                    float wv = ws[(co * 3 + ci) * 25 + dy * 5 + dx];
                    acc[co][0][0] = fmaf(wv, S[dy][dx],         acc[co][0][0]);
                    acc[co][0][1] = fmaf(wv, S[dy][dx + 1],     acc[co][0][1]);
                    acc[co][1][0] = fmaf(wv, S[dy + 1][dx],     acc[co][1][0]);
                    acc[co][1][1] = fmaf(wv, S[dy + 1][dx + 1], acc[co][1][1]);
                }
            }
        }
    }
#pragma unroll
    for (int co = 0; co < 4; ++co) {
        float v00 = leaky(acc[co][0][0]), v01 = leaky(acc[co][0][1]);
        float v10 = leaky(acc[co][1][0]), v11 = leaky(acc[co][1][1]);
        if (n >= 2) {
            float* op = c2 + ((size_t)((n - 2) * 4 + co)) * R * R + (Y0 + 2 * qy) * R + X0 + 2 * qx;
            float2 a; a.x = v00; a.y = v01; *(float2*)op = a;
            float2 b2; b2.x = v10; b2.y = v11; *(float2*)(op + R) = b2;
        }
        float pv = fmaxf(fmaxf(v00, v01), fmaxf(v10, v11));
        pout[((size_t)(n * 4 + co)) * 16384 + (16 * tileY + qy) * 128 + 16 * tileX + qx] = pv;
    }
}

// ===== Staged encoder for levels 1-2: 16x16 conv tile, 1 px x COG co per thread =====
// pin layout [4][CI][R][R]. Halo 20x20xCI staged; weights co-innermost (b128/tap).
template<int R, int CI, int CO, int COG, int NCOG>
__global__ void __launch_bounds__(256) enc_staged_k(
    const float* __restrict__ pin, const float* __restrict__ w,
    const float* __restrict__ bias, float* __restrict__ c2, float* __restrict__ pout)
{
    constexpr int TILES = R / 16, Wt = R / 2;
    __shared__ float ss[CI * 400];
    __shared__ float ws4[CI * 25 * COG];
    __shared__ float pe[COG * 256];

    int t = threadIdx.x;
    int by = blockIdx.y;
    int n = by / NCOG, cog = by % NCOG;
    int tileY = blockIdx.x / TILES, tileX = blockIdx.x % TILES;
    int Y0 = 16 * tileY, X0 = 16 * tileX;

    for (int i = t; i < CI * 25 * COG; i += 256) {
        int cg = i % COG, idx = i / COG;
        ws4[idx * COG + cg] = w[(cog * COG + cg) * CI * 25 + idx];
    }
    const float* base = pin + (size_t)n * CI * R * R;
#pragma unroll 2
    for (int i = t; i < CI * 400; i += 256) {
        int c = i / 400, rem = i - c * 400;
        int r = rem / 20, col = rem - r * 20;
        int gy = Y0 - 2 + r, gx = X0 - 2 + col;
        float v = 0.f;
        if (gy >= 0 && gy < R && gx >= 0 && gx < R)
            v = base[(size_t)c * R * R + gy * R + gx];
        ss[i] = v;
    }
    __syncthreads();

    int qx = t & 15, qy = t >> 4;
    float acc[COG];
#pragma unroll
    for (int cg = 0; cg < COG; ++cg) acc[cg] = bias[cog * COG + cg];

#pragma unroll 4
    for (int ci = 0; ci < CI; ++ci) {
        const float* sp = &ss[ci * 400 + qy * 20 + qx];
        float S[5][5];
#pragma unroll
        for (int i = 0; i < 5; ++i)
#pragma unroll
            for (int j = 0; j < 5; ++j) S[i][j] = sp[i * 20 + j];
#pragma unroll
        for (int dy = 0; dy < 5; ++dy) {
#pragma unroll
            for (int dx = 0; dx < 5; ++dx) {
                float4 wv = *(const float4*)&ws4[(ci * 25 + dy * 5 + dx) * COG];
                float sv = S[dy][dx];
                acc[0] = fmaf(wv.x, sv, acc[0]);
                acc[1] = fmaf(wv.y, sv, acc[1]);
                acc[2] = fmaf(wv.z, sv, acc[2]);
                acc[3] = fmaf(wv.w, sv, acc[3]);
            }
        }
    }

#pragma unroll
    for (int cg = 0; cg < COG; ++cg) {
        float v = leaky(acc[cg]);
        if (n >= 2)
            c2[((size_t)((n - 2) * CO + cog * COG + cg)) * R * R + (Y0 + qy) * R + X0 + qx] = v;
        pe[cg * 256 + t] = v;
    }
    __syncthreads();
    if (t < 64) {
        int py = t >> 3, px = t & 7;
        int b0 = (2 * py) * 16 + 2 * px;
#pragma unroll
        for (int cg = 0; cg < COG; ++cg) {
            const float* pp = &pe[cg * 256];
            float pv = fmaxf(fmaxf(pp[b0], pp[b0 + 1]), fmaxf(pp[b0 + 16], pp[b0 + 17]));
            pout[((size_t)(n * CO + cog * COG + cg)) * Wt * Wt + (8 * tileY + py) * Wt + 8 * tileX + px] = pv;
        }
    }
}

// ================= enc_body (used by bigprep for enc3) ===============================
template<int R, int CI, int CO, int COG>
__device__ __forceinline__ void enc_body(
    const float* __restrict__ src1, const float* __restrict__ src2,
    const float* __restrict__ w, const float* __restrict__ bias,
    float* __restrict__ c2, float* __restrict__ pout, int bx)
{
    constexpr int W = R, H = R, Wt = R / 2;
    constexpr int RPB = 256 / Wt;
    __shared__ float ws[COG * CI * 25];
    __shared__ float pl[(RPB / 2) * COG * Wt];

    int t = threadIdx.x;
    int gid = bx * 256 + t;
    int col = gid % Wt;
    int y = (gid / Wt) % H;
    int n = (gid / (Wt * H)) & 3;
    int g = gid / (Wt * H * 4);

    for (int i = t; i < COG * CI * 25; i += 256) ws[i] = w[g * COG * CI * 25 + i];
    __syncthreads();

    const float* sp = (n < 2) ? (src1 + (size_t)n * CI * H * W)
                              : (src2 + (size_t)(n - 2) * CI * H * W);
    int x0 = col * 2;

    float acc[COG][2];
#pragma unroll
    for (int cg = 0; cg < COG; ++cg) { float b0 = bias[g * COG + cg]; acc[cg][0] = b0; acc[cg][1] = b0; }

    bool okr[5], okc[3];
#pragma unroll
    for (int i = 0; i < 5; ++i) { int yy = y + i - 2; okr[i] = (yy >= 0) && (yy < H); }
#pragma unroll
    for (int j = 0; j < 3; ++j) { int xx = x0 + 2 * j - 2; okc[j] = (xx >= 0) && (xx < W); }

#pragma unroll 4
    for (int ci = 0; ci < CI; ++ci) {
        const float* s = sp + ci * H * W + (y - 2) * W + (x0 - 2);
        float p[5][6];
#pragma unroll
        for (int i = 0; i < 5; ++i) {
#pragma unroll
            for (int j = 0; j < 3; ++j) {
                if (okr[i] & okc[j]) {
                    float2 v = *(const float2*)(s + i * W + 2 * j);
                    p[i][2 * j] = v.x; p[i][2 * j + 1] = v.y;
                } else { p[i][2 * j] = 0.f; p[i][2 * j + 1] = 0.f; }
            }
        }
#pragma unroll
        for (int cg = 0; cg < COG; ++cg) {
#pragma unroll
            for (int dy = 0; dy < 5; ++dy) {
#pragma unroll
                for (int dx = 0; dx < 5; ++dx) {
                    float wv = ws[(cg * CI + ci) * 25 + dy * 5 + dx];
                    acc[cg][0] = fmaf(wv, p[dy][dx],     acc[cg][0]);
                    acc[cg][1] = fmaf(wv, p[dy][dx + 1], acc[cg][1]);
                }
            }
        }
    }

    int r = t / Wt;
    float m[COG];
#pragma unroll
    for (int cg = 0; cg < COG; ++cg) {
        float v0 = leaky(acc[cg][0]), v1 = leaky(acc[cg][1]);
        m[cg] = fmaxf(v0, v1);
        if (n >= 2) {
            float2 stv; stv.x = v0; stv.y = v1;
            *(float2*)(c2 + ((size_t)((n - 2) * CO + g * COG + cg)) * H * W + y * W + x0) = stv;
        }
    }
    if (r & 1) {
#pragma unroll
        for (int cg = 0; cg < COG; ++cg)
            pl[((r >> 1) * COG + cg) * Wt + col] = m[cg];
    }
    __syncthreads();
    if (!(r & 1)) {
#pragma unroll
        for (int cg = 0; cg < COG; ++cg) {
            float pv = fmaxf(m[cg], pl[((r >> 1) * COG + cg) * Wt + col]);
            pout[((size_t)(n * CO + g * COG + cg)) * Wt * Wt + (y >> 1) * Wt + col] = pv;
        }
    }
}

// ================= Attention body ====================================================
template<int C, int RP, int SHIFT>
__device__ __forceinline__ void attn_body(
    const float* __restrict__ pool, const int* __restrict__ pts,
    float* __restrict__ out, int tile, int b)
{
    constexpr int P = RP * RP;
    __shared__ float qs[32 * C];
    int t = threadIdx.x;
    if (t < 32) {
        int l = t;
        int py = pts[(b * 32 + l) * 2 + 0] >> SHIFT;
        int px = pts[(b * 32 + l) * 2 + 1] >> SHIFT;
        const float* qp = pool + (size_t)(b * C) * P + py * RP + px;
        float v[C]; float s = 0.f;
#pragma unroll
        for (int c = 0; c < C; ++c) { v[c] = qp[c * P]; s += v[c] * v[c]; }
        float invn = 1.f / fmaxf(sqrtf(s), 1e-8f);
#pragma unroll
        for (int c = 0; c < C; ++c) qs[l * C + c] = v[c] * invn;
    }
    __syncthreads();
    int p = tile * 256 + t;
    const float* hp = pool + (size_t)((2 + b) * C) * P + p;
    float v[C]; float s = 0.f;
#pragma unroll
    for (int c = 0; c < C; ++c) { v[c] = hp[c * P]; s += v[c] * v[c]; }
    float invn2 = 1.f / fmaxf(sqrtf(s), 1e-8f);
#pragma unroll 4
    for (int l = 0; l < 32; ++l) {
        float d = 0.f;
#pragma unroll
        for (int c = 0; c < C; ++c) d = fmaf(v[c], qs[l * C + c], d);
        out[(size_t)(b * 32 + l) * P + p] = d * invn2;
    }
}

// ================= Parity feature-base bodies ========================================
template<int R, int CI, int CINW, int CO, int COG>
__device__ __forceinline__ void fb_body(
    const float* __restrict__ in, const float* __restrict__ w,
    const float* __restrict__ bias, float* __restrict__ fb,
    int par, int tile, int cog)
{
    constexpr int QD = R / 2;
    __shared__ float ws[COG * CI * 9];
    int t = threadIdx.x;
    for (int i = t; i < COG * CI * 9; i += 256) {
        int co = i / (CI * 9), rem = i - co * (CI * 9);
        ws[i] = w[(cog * COG + co) * CINW * 9 + (CINW - CI) * 9 + rem];
    }
    __syncthreads();
    int q = tile * 256 + t;
    int qx = q % QD, qy = q / QD;
    const float* ip = in + (size_t)par * CI * R * R;
    float acc[COG][2][2];
#pragma unroll
    for (int co = 0; co < COG; ++co) {
        float b0 = bias[cog * COG + co];
        acc[co][0][0] = b0; acc[co][0][1] = b0; acc[co][1][0] = b0; acc[co][1][1] = b0;
    }
    bool fr[4], fc[4];
#pragma unroll
    for (int i = 0; i < 4; ++i) {
        int yy = 2 * qy - 1 + i; fr[i] = (yy >= 0) && (yy < R);
        int xx = 2 * qx - 1 + i; fc[i] = (xx >= 0) && (xx < R);
    }
#pragma unroll 4
    for (int ci = 0; ci < CI; ++ci) {
        const float* bp = ip + (size_t)ci * R * R + (2 * qy - 1) * R + (2 * qx - 1);
        float F[4][4];
#pragma unroll
        for (int i = 0; i < 4; ++i)
#pragma unroll
            for (int j = 0; j < 4; ++j)
                F[i][j] = (fr[i] & fc[j]) ? bp[i * R + j] : 0.f;
#pragma unroll
        for (int co = 0; co < COG; ++co) {
#pragma unroll
            for (int dy = 0; dy < 3; ++dy) {
#pragma unroll
                for (int dx = 0; dx < 3; ++dx) {
                    float wv = ws[(co * CI + ci) * 9 + dy * 3 + dx];
                    acc[co][0][0] = fmaf(wv, F[dy][dx],         acc[co][0][0]);
                    acc[co][0][1] = fmaf(wv, F[dy][dx + 1],     acc[co][0][1]);
                    acc[co][1][0] = fmaf(wv, F[dy + 1][dx],     acc[co][1][0]);
                    acc[co][1][1] = fmaf(wv, F[dy + 1][dx + 1], acc[co][1][1]);
                }
            }
        }
    }
#pragma unroll
    for (int co = 0; co < COG; ++co) {
        float* op = fb + ((size_t)(par * CO + cog * COG + co)) * R * R + (2 * qy) * R + 2 * qx;
        float2 a; a.x = acc[co][0][0]; a.y = acc[co][0][1]; *(float2*)op = a;
        float2 b2; b2.x = acc[co][1][0]; b2.y = acc[co][1][1]; *(float2*)(op + R) = b2;
    }
}

__device__ __forceinline__ void fb0_body(
    const float* __restrict__ p3, const float* __restrict__ c2_3,
    const float* __restrict__ w, const float* __restrict__ bias,
    float* __restrict__ fb0, int par, int tile, int cog)
{
    __shared__ float ws0[4 * 33 * 9];
    int t = threadIdx.x;
    for (int i = t; i < 4 * 33 * 9; i += 256) ws0[i] = w[cog * 4 * 33 * 9 + i];
    __syncthreads();
    int px = tile * 256 + t;
    int x = px & 31, y = px >> 5;
    const float* prevp = p3 + (size_t)(2 + par) * 16 * 256;
    const float* featp = c2_3 + (size_t)par * 16 * 1024;
    float acc[4];
#pragma unroll
    for (int co = 0; co < 4; ++co) acc[co] = bias[cog * 4 + co];

    bool oky[3], okx[3];
    int py[3], pxh[3];
#pragma unroll
    for (int i = 0; i < 3; ++i) {
        int iy = y - 1 + i; oky[i] = (iy >= 0) && (iy < 32); py[i] = (iy >= 0 ? iy : 0) >> 1;
        int ix = x - 1 + i; okx[i] = (ix >= 0) && (ix < 32); pxh[i] = (ix >= 0 ? ix : 0) >> 1;
    }
#pragma unroll 4
    for (int ci = 0; ci < 16; ++ci) {
        const float* pp = prevp + ci * 256;
        float V[3][3];
#pragma unroll
        for (int i = 0; i < 3; ++i)
#pragma unroll
            for (int j = 0; j < 3; ++j)
                V[i][j] = (oky[i] & okx[j]) ? pp[py[i] * 16 + pxh[j]] : 0.f;
#pragma unroll
        for (int co = 0; co < 4; ++co) {
#pragma unroll
            for (int tap = 0; tap < 9; ++tap)
                acc[co] = fmaf(ws0[(co * 33 + ci) * 9 + tap], V[tap / 3][tap % 3], acc[co]);
        }
    }
#pragma unroll 4
    for (int cf = 0; cf < 16; ++cf) {
        const float* fp = featp + cf * 1024;
        float F[3][3];
#pragma unroll
        for (int i = 0; i < 3; ++i)
#pragma unroll
            for (int j = 0; j < 3; ++j) {
                int iy = y - 1 + i, ix = x - 1 + j;
                F[i][j] = (oky[i] & okx[j]) ? fp[iy * 32 + ix] : 0.f;
            }
#pragma unroll
        for (int co = 0; co < 4; ++co) {
#pragma unroll
            for (int tap = 0; tap < 9; ++tap)
                acc[co] = fmaf(ws0[(co * 33 + 17 + cf) * 9 + tap], F[tap / 3][tap % 3], acc[co]);
        }
    }
#pragma unroll
    for (int co = 0; co < 4; ++co)
        fb0[((size_t)(par * 16 + cog * 4 + co)) * 1024 + y * 32 + x] = acc[co];
}

// ========== bigprep: enc3 + attn levels 0-2 + fb1/fb2/fb3 in one launch =============
__global__ void __launch_bounds__(256) bigprep_k(
    const float* __restrict__ p0, const float* __restrict__ p1,
    const float* __restrict__ p2, const int* __restrict__ pts,
    const float* __restrict__ ew3, const float* __restrict__ eb3,
    float* __restrict__ c2_3, float* __restrict__ p3,
    const float* __restrict__ c2_0, const float* __restrict__ c2_1,
    const float* __restrict__ c2_2,
    const float* __restrict__ dw1, const float* __restrict__ db1,
    const float* __restrict__ dw2, const float* __restrict__ db2,
    const float* __restrict__ dw3, const float* __restrict__ db3,
    float* __restrict__ at0, float* __restrict__ at1, float* __restrict__ at2,
    float* __restrict__ fb1, float* __restrict__ fb2, float* __restrict__ fb3)
{
    int bx = blockIdx.x;
    if (bx < 128) {
        enc_body<32, 16, 16, 1>(p2, p2 + (size_t)2 * 16 * 32 * 32, ew3, eb3, c2_3, p3, bx);
    } else if (bx < 256) {
        int r = bx - 128; attn_body<4, 128, 1>(p0, pts, at0, r >> 1, r & 1);
    } else if (bx < 288) {
        int r = bx - 256; attn_body<8, 64, 2>(p1, pts, at1, r >> 1, r & 1);
    } else if (bx < 296) {
        int r = bx - 288; attn_body<16, 32, 3>(p2, pts, at2, r >> 1, r & 1);
    } else if (bx < 424) {
        int sub = bx - 296; int par = sub >> 6, tile = sub & 63;
        fb_body<256, 4, 9, 1, 1>(c2_0, dw3, db3, fb3, par, tile, 0);
    } else if (bx < 456) {
        int sub = bx - 424; int par = sub >> 4, tile = sub & 15;
        fb_body<128, 8, 17, 4, 4>(c2_1, dw2, db2, fb2, par, tile, 0);
    } else {
        int sub = bx - 456; int cog = sub & 1, tile = (sub >> 1) & 3, par = sub >> 3;
        fb_body<64, 16, 33, 8, 4>(c2_2, dw1, db1, fb1, par, tile, cog);
    }
}

// ========== prep2: attn level 3 + fb0 (need enc3 outputs) ===========================
__global__ void __launch_bounds__(256) prep2_k(
    const float* __restrict__ p3, const float* __restrict__ c2_3,
    const int* __restrict__ pts,
    const float* __restrict__ dw0, const float* __restrict__ db0,
    float* __restrict__ at3, float* __restrict__ fb0)
{
    int bx = blockIdx.x;
    if (bx < 2) {
        attn_body<16, 16, 4>(p3, pts, at3, bx >> 1, bx & 1);
    } else {
        int sub = bx - 2; int cog = sub & 3, tile = (sub >> 2) & 3, par = sub >> 4;
        fb0_body(p3, c2_3, dw0, db0, fb0, par, tile, cog);
    }
}

// ================= dec0k: out = leaky(fb0[k&1] + conv(up(at3[k]))) ===================
__global__ void __launch_bounds__(256) dec0k_k(
    const float* __restrict__ at3, const float* __restrict__ fb0,
    const float* __restrict__ w, float* __restrict__ out)
{
    __shared__ float ws4[9 * 16];
    int t = threadIdx.x;
    if (t < 144) {
        int tap = t / 16, co = t - (t / 16) * 16;
        ws4[tap * 16 + co] = w[co * 33 * 9 + 16 * 9 + tap];
    }
    __syncthreads();
    int gid = blockIdx.x;
    int k = gid >> 2, tile = gid & 3;
    int px = tile * 256 + t;
    int x = px & 31, y = px >> 5;
    int par = k & 1;
    const float* ap = at3 + (size_t)k * 256;

    float A[3][3];
#pragma unroll
    for (int i = 0; i < 3; ++i) {
        int iy = y - 1 + i; bool oy = (iy >= 0) && (iy < 32); int py = (iy >= 0 ? iy : 0) >> 1;
#pragma unroll
        for (int j = 0; j < 3; ++j) {
            int ix = x - 1 + j; bool ox = (ix >= 0) && (ix < 32); int qx = (ix >= 0 ? ix : 0) >> 1;
            A[i][j] = (oy && ox) ? ap[py * 16 + qx] : 0.f;
        }
    }
    float acc[16];
#pragma unroll
    for (int co = 0; co < 16; ++co)
        acc[co] = fb0[((size_t)(par * 16 + co)) * 1024 + y * 32 + x];
#pragma unroll
    for (int tap = 0; tap < 9; ++tap) {
        float av = A[tap / 3][tap % 3];
#pragma unroll
        for (int c4 = 0; c4 < 4; ++c4) {
            float4 wv = *(const float4*)&ws4[tap * 16 + c4 * 4];
            acc[c4 * 4 + 0] = fmaf(wv.x, av, acc[c4 * 4 + 0]);
            acc[c4 * 4 + 1] = fmaf(wv.y, av, acc[c4 * 4 + 1]);
            acc[c4 * 4 + 2] = fmaf(wv.z, av, acc[c4 * 4 + 2]);
            acc[c4 * 4 + 3] = fmaf(wv.w, av, acc[c4 * 4 + 3]);
        }
    }
#pragma unroll
    for (int co = 0; co < 16; ++co)
        out[((size_t)(k * 16 + co)) * 1024 + y * 32 + x] = leaky(acc[co]);
}

// ================= dec1k: 16x8 tile, 4 same-parity k x 2 co, half-res only ===========
__global__ void __launch_bounds__(256, 4) dec1k_k(
    const float* __restrict__ prev, const float* __restrict__ attn,
    const float* __restrict__ fb1, const float* __restrict__ w,
    float* __restrict__ out)
{
    constexpr int R = 64, CP = 16, CIN = 33, Rh = 32, CO = 8, COG = 4;
    __shared__ float ws[17 * 9 * COG];
    __shared__ float sh4[17 * 60 * 4];

    int t = threadIdx.x;
    int bz = blockIdx.y;
    int kg = bz >> 1, cog = bz & 1;
    int p = kg & 1;
    int kbase = (kg >> 1) * 8 + p;
    int tileY = blockIdx.x >> 2, tileX = blockIdx.x & 3;
    int Y0 = 8 * tileY, X0 = 16 * tileX;
    int hy0 = 4 * tileY - 1, hx0 = 8 * tileX - 1;

    for (int i = t; i < 17 * 9 * COG; i += 256) {
        int col = i & 3, idx = i >> 2;
        ws[idx * 4 + col] = w[(cog * COG + col) * CIN * 9 + idx];
    }
#pragma unroll 2
    for (int i = t; i < 17 * 60; i += 256) {
        int c = i / 60, rem = i - c * 60;
        int r = rem / 10, col = rem - r * 10;
        int gy = hy0 + r, gx = hx0 + col;
        bool ok = (gy >= 0) && (gy < Rh) && (gx >= 0) && (gx < Rh);
        int off = gy * Rh + gx;
        float4 v4; v4.x = 0.f; v4.y = 0.f; v4.z = 0.f; v4.w = 0.f;
        if (ok) {
            if (c < CP) {
                v4.x = prev[((size_t)((kbase + 0) * CP + c)) * Rh * Rh + off];
                v4.y = prev[((size_t)((kbase + 2) * CP + c)) * Rh * Rh + off];
                v4.z = prev[((size_t)((kbase + 4) * CP + c)) * Rh * Rh + off];
                v4.w = prev[((size_t)((kbase + 6) * CP + c)) * Rh * Rh + off];
            } else {
                v4.x = attn[(size_t)(kbase + 0) * Rh * Rh + off];
                v4.y = attn[(size_t)(kbase + 2) * Rh * Rh + off];
                v4.z = attn[(size_t)(kbase + 4) * Rh * Rh + off];
                v4.w = attn[(size_t)(kbase + 6) * Rh * Rh + off];
            }
        }
        *(float4*)&sh4[i * 4] = v4;
    }
    __syncthreads();

    int px = t & 127, copair = t >> 7;
    int qx = px & 15, qy = px >> 4;

    float acc[4][2];
#pragma unroll
    for (int c2 = 0; c2 < 2; ++c2) {
        float fv = fb1[((size_t)(p * CO + cog * COG + copair * 2 + c2)) * 4096 + (Y0 + qy) * R + X0 + qx];
#pragma unroll
        for (int j = 0; j < 4; ++j) acc[j][c2] = fv;
    }

    int rr[3] = {(qy + 1) >> 1, (qy + 2) >> 1, (qy + 3) >> 1};
    int cc[3] = {(qx + 1) >> 1, (qx + 2) >> 1, (qx + 3) >> 1};
    int pofs[3][3];
#pragma unroll
    for (int i = 0; i < 3; ++i)
#pragma unroll
        for (int j2 = 0; j2 < 3; ++j2)
            pofs[i][j2] = (rr[i] * 10 + cc[j2]) * 4;

#pragma unroll 4
    for (int ci = 0; ci < 17; ++ci) {
        const float* hp = &sh4[ci * 240];
        float4 P4[3][3];
#pragma unroll
        for (int i = 0; i < 3; ++i)
#pragma unroll
            for (int j2 = 0; j2 < 3; ++j2)
                P4[i][j2] = *(const float4*)&hp[pofs[i][j2]];
#pragma unroll
        for (int dy = 0; dy < 3; ++dy) {
#pragma unroll
            for (int dx = 0; dx < 3; ++dx) {
                float2 wv = *(const float2*)&ws[(ci * 9 + dy * 3 + dx) * 4 + copair * 2];
                acc[0][0] = fmaf(wv.x, P4[dy][dx].x, acc[0][0]);
                acc[1][0] = fmaf(wv.x, P4[dy][dx].y, acc[1][0]);
                acc[2][0] = fmaf(wv.x, P4[dy][dx].z, acc[2][0]);
                acc[3][0] = fmaf(wv.x, P4[dy][dx].w, acc[3][0]);
                acc[0][1] = fmaf(wv.y, P4[dy][dx].x, acc[0][1]);
                acc[1][1] = fmaf(wv.y, P4[dy][dx].y, acc[1][1]);
                acc[2][1] = fmaf(wv.y, P4[dy][dx].z, acc[2][1]);
                acc[3][1] = fmaf(wv.y, P4[dy][dx].w, acc[3][1]);
            }
        }
    }

#pragma unroll
    for (int j = 0; j < 4; ++j) {
        int k = kbase + 2 * j;
#pragma unroll
        for (int c2 = 0; c2 < 2; ++c2) {
            int co = cog * COG + copair * 2 + c2;
            out[((size_t)(k * CO + co)) * 4096 + (Y0 + qy) * R + X0 + qx] = leaky(acc[j][c2]);
        }
    }
}

// ================= dec2k/dec3k: half-res conv + fb init, 4-k blocks ==================
template<int R, int CP, int CO, int CINW, int MINW, bool DOLEAKY>
__global__ void __launch_bounds__(256, MINW) dechalf_k(
    const float* __restrict__ prev, const float* __restrict__ attn,
    const float* __restrict__ fb, const float* __restrict__ w,
    float* __restrict__ out)
{
    constexpr int Rh = R / 2, TX = R / 16;
    constexpr bool PACKW = (CO == 4);
    __shared__ float sh[4][(CP + 1) * 100];
    __shared__ float ws4[PACKW ? (CP + 1) * 9 * 4 : 4];

    int t = threadIdx.x;
    int kg = blockIdx.y;
    int p = kg & 1;
    int kbase = (kg >> 1) * 8 + p;
    int tileY = blockIdx.x / TX, tileX = blockIdx.x % TX;
    int Y0 = 16 * tileY, X0 = 16 * tileX;
    int hy0 = 8 * tileY - 1, hx0 = 8 * tileX - 1;

    if (PACKW) {
        for (int i = t; i < (CP + 1) * 9 * 4; i += 256) {
            int co = i & 3, idx = i >> 2;
            ws4[i] = w[co * CINW * 9 + idx];
        }
    }
#pragma unroll 2
    for (int i = t; i < CP * 100; i += 256) {
        int c = i / 100, rem = i - c * 100;
        int r = rem / 10, col = rem - r * 10;
        int gy = hy0 + r, gx = hx0 + col;
        bool ok = (gy >= 0) && (gy < Rh) && (gx >= 0) && (gx < Rh);
        int off = gy * Rh + gx;
#pragma unroll
        for (int j = 0; j < 4; ++j) {
            float v = 0.f;
            if (ok) v = prev[((size_t)((kbase + 2 * j) * CP + c)) * Rh * Rh + off];
            sh[j][i] = v;
        }
    }
    if (t < 100) {
        int r = t / 10, col = t - r * 10;
        int gy = hy0 + r, gx = hx0 + col;
        bool ok = (gy >= 0) && (gy < Rh) && (gx >= 0) && (gx < Rh);
        int off = gy * Rh + gx;
#pragma unroll
        for (int j = 0; j < 4; ++j) {
            float v = 0.f;
            if (ok) v = attn[(size_t)(kbase + 2 * j) * Rh * Rh + off];
            sh[j][CP * 100 + t] = v;
        }
    }
    __syncthreads();

    int ksub = t >> 6, q = t & 63, qx = q & 7, qy = q >> 3;
    int k = kbase + 2 * ksub;

    float acc[CO][2][2];
#pragma unroll
    for (int co = 0; co < CO; ++co) {
        const float* fp = fb + ((size_t)(p * CO + co)) * R * R + (Y0 + 2 * qy) * R + X0 + 2 * qx;
        float2 r0 = *(const float2*)fp;
        float2 r1 = *(const float2*)(fp + R);
        acc[co][0][0] = r0.x; acc[co][0][1] = r0.y;
        acc[co][1][0] = r1.x; acc[co][1][1] = r1.y;
    }

#pragma unroll
    for (int ci = 0; ci < CP + 1; ++ci) {
        const float* hp = &sh[ksub][ci * 100 + qy * 10 + qx];
        float P[3][3];
#pragma unroll
        for (int i = 0; i < 3; ++i)
#pragma unroll
            for (int j = 0; j < 3; ++j) P[i][j] = hp[i * 10 + j];
#pragma unroll
        for (int dy = 0; dy < 3; ++dy) {
#pragma unroll
            for (int dx = 0; dx < 3; ++dx) {
                float p00 = P[(dy + 1) >> 1][(dx + 1) >> 1];
                float p01 = P[(dy + 1) >> 1][(dx + 2) >> 1];
                float p10 = P[(dy + 2) >> 1][(dx + 1) >> 1];
                float p11 = P[(dy + 2) >> 1][(dx + 2) >> 1];
                if (PACKW) {
                    float4 wv = *(const float4*)&ws4[(ci * 9 + dy * 3 + dx) * 4];
                    const float* wvp = (const float*)&wv;
#pragma unroll
                    for (int co = 0; co < CO; ++co) {
                        acc[co][0][0] = fmaf(wvp[co], p00, acc[co][0][0]);
                        acc[co][0][1] = fmaf(wvp[co], p01, acc[co][0][1]);
                        acc[co][1][0] = fmaf(wvp[co], p10, acc[co][1][0]);
                        acc[co][1][1] = fmaf(wvp[co], p11, acc[co][1][1]);
                    }
                } else {
                    float wv = w[ci * 9 + dy * 3 + dx];
                    acc[0][0][0] = fmaf(wv, p00, acc[0][0][0]);
                    acc[0][0][1] = fmaf(wv, p01, acc[0][0][1]);
                    acc[0][1][0] = fmaf(wv, p10, acc[0][1][0]);
                    acc[0][1][1] = fmaf(wv, p11, acc[0][1][1]);
                }
            }
        }
    }

#pragma unroll
    for (int co = 0; co < CO; ++co) {
        float v00 = acc[co][0][0], v01 = acc[co][0][1];
        float v10 = acc[co][1][0], v11 = acc[co][1][1];
        if (DOLEAKY) { v00 = leaky(v00); v01 = leaky(v01); v10 = leaky(v10); v11 = leaky(v11); }
        float* op = out + ((size_t)(k * CO + co)) * R * R + (Y0 + 2 * qy) * R + X0 + 2 * qx;
        float2 a; a.x = v00; a.y = v01; *(float2*)op = a;
        float2 b2; b2.x = v10; b2.y = v11; *(float2*)(op + R) = b2;
    }
}

extern "C" void kernel_launch(void* const* d_in, const int* in_sizes, int n_in,
                              void* d_out, int out_size, void* d_ws, size_t ws_size,
                              hipStream_t stream)
{
    (void)in_sizes; (void)n_in; (void)out_size; (void)ws_size;
    const float* x1 = (const float*)d_in[0];
    const float* x2 = (const float*)d_in[1];
    const int* pts = (const int*)d_in[2];
    const float* ew[4] = {(const float*)d_in[3], (const float*)d_in[5],
                          (const float*)d_in[7], (const float*)d_in[9]};
    const float* eb[4] = {(const float*)d_in[4], (const float*)d_in[6],
                          (const float*)d_in[8], (const float*)d_in[10]};
    const float* dw[4] = {(const float*)d_in[11], (const float*)d_in[13],
                          (const float*)d_in[15], (const float*)d_in[17]};
    const float* db[4] = {(const float*)d_in[12], (const float*)d_in[14],
                          (const float*)d_in[16], (const float*)d_in[18]};

    float* wsp = (float*)d_ws;
    size_t off = 0;
    auto A = [&](size_t n) { float* p = wsp + off; off += n; return p; };

    float* p0 = A((size_t)4 * 4 * 128 * 128);
    float* p1 = A((size_t)4 * 8 * 64 * 64);
    float* p2 = A((size_t)4 * 16 * 32 * 32);
    float* p3 = A((size_t)4 * 16 * 16 * 16);
    float* c2_0 = A((size_t)2 * 4 * 256 * 256);
    float* c2_1 = A((size_t)2 * 8 * 128 * 128);
    float* c2_2 = A((size_t)2 * 16 * 64 * 64);
    float* c2_3 = A((size_t)2 * 16 * 32 * 32);
    float* at0 = A((size_t)64 * 128 * 128);
    float* at1 = A((size_t)64 * 64 * 64);
    float* at2 = A((size_t)64 * 32 * 32);
    float* at3 = A((size_t)64 * 16 * 16);
    float* dec0 = A((size_t)64 * 16 * 32 * 32);
    float* dec1 = A((size_t)64 * 8 * 64 * 64);
    float* dec2 = A((size_t)64 * 4 * 128 * 128);
    float* fb0 = A((size_t)2 * 16 * 32 * 32);
    float* fb1 = A((size_t)2 * 8 * 64 * 64);
    float* fb2 = A((size_t)2 * 4 * 128 * 128);
    float* fb3 = A((size_t)2 * 256 * 256);
    float* outp = (float*)d_out;

    // ---- Encoder levels 0-2 ----
    { dim3 g(64, 4); enc0_k<<<g, 256, 0, stream>>>(x1, x2, ew[0], eb[0], c2_0, p0); }
    // enc1: 64 tiles x (4n x 2 cog) = 512 blocks, staged
    { dim3 g(64, 8); enc_staged_k<128, 4, 8, 4, 2><<<g, 256, 0, stream>>>(p0, ew[1], eb[1], c2_1, p1); }
    // enc2: 16 tiles x (4n x 4 cog) = 256 blocks, staged
    { dim3 g(16, 16); enc_staged_k<64, 8, 16, 4, 4><<<g, 256, 0, stream>>>(p1, ew[2], eb[2], c2_2, p2); }

    // ---- bigprep: enc3 + attn levels 0-2 + fb1/fb2/fb3 ----
    bigprep_k<<<472, 256, 0, stream>>>(p0, p1, p2, pts, ew[3], eb[3], c2_3, p3,
                                       c2_0, c2_1, c2_2,
                                       dw[1], db[1], dw[2], db[2], dw[3], db[3],
                                       at0, at1, at2, fb1, fb2, fb3);

    // ---- prep2: attn3 + fb0 ----
    prep2_k<<<34, 256, 0, stream>>>(p3, c2_3, pts, dw[0], db[0], at3, fb0);

    // ---- Per-k decoder ----
    dec0k_k<<<256, 256, 0, stream>>>(at3, fb0, dw[0], dec0);
    { dim3 g(32, 32); dec1k_k<<<g, 256, 0, stream>>>(dec0, at2, fb1, dw[1], dec1); }
    { dim3 g(64, 16); dechalf_k<128, 8, 4, 17, 4, true><<<g, 256, 0, stream>>>(dec1, at1, fb2, dw[2], dec2); }
    { dim3 g(256, 16); dechalf_k<256, 4, 1, 9, 5, false><<<g, 256, 0, stream>>>(dec2, at0, fb3, dw[3], outp); }
}

// Round 18
// 130.842 us; speedup vs baseline: 1.0687x; 1.0687x over previous
//
#include <hip/hip_runtime.h>
#include <cstdint>

__device__ __forceinline__ float leaky(float v) { return v >= 0.f ? v : 0.01f * v; }

// ================= Encoder level 0: staged conv5x5 + leaky + pool ====================
__global__ void __launch_bounds__(256) enc0_k(
    const float* __restrict__ x1, const float* __restrict__ x2,
    const float* __restrict__ w, const float* __restrict__ bias,
    float* __restrict__ c2, float* __restrict__ pout)
{
    constexpr int R = 256;
    __shared__ float ss[3 * 36 * 36];
    __shared__ float ws[4 * 3 * 25 + 4];
    int t = threadIdx.x;
    int n = blockIdx.y;
    int tileY = blockIdx.x >> 3, tileX = blockIdx.x & 7;
    int Y0 = 32 * tileY, X0 = 32 * tileX;
    const float* src = (n < 2) ? x1 + (size_t)n * 3 * R * R
                               : x2 + (size_t)(n - 2) * 3 * R * R;

    for (int i = t; i < 300; i += 256) ws[i] = w[i];
    if (t < 4) ws[300 + t] = bias[t];
    for (int ci = 0; ci < 3; ++ci) {
        const float* sp = src + (size_t)ci * R * R;
        for (int i = t; i < 1296; i += 256) {
            int r = i / 36, col = i - r * 36;
            int gy = Y0 - 2 + r, gx = X0 - 2 + col;
            float v = 0.f;
            if (gy >= 0 && gy < R && gx >= 0 && gx < R) v = sp[gy * R + gx];
            ss[ci * 1296 + i] = v;
        }
    }
    __syncthreads();

    int qx = t & 15, qy = t >> 4;
    float acc[4][2][2];
#pragma unroll
    for (int co = 0; co < 4; ++co) {
        float b0 = ws[300 + co];
        acc[co][0][0] = b0; acc[co][0][1] = b0; acc[co][1][0] = b0; acc[co][1][1] = b0;
    }
#pragma unroll
    for (int ci = 0; ci < 3; ++ci) {
        const float* sp = &ss[ci * 1296 + (2 * qy) * 36 + 2 * qx];
        float S[6][6];
#pragma unroll
        for (int i = 0; i < 6; ++i)
#pragma unroll
            for (int j = 0; j < 6; ++j) S[i][j] = sp[i * 36 + j];
#pragma unroll
        for (int co = 0; co < 4; ++co) {
#pragma unroll
            for (int dy = 0; dy < 5; ++dy) {
#pragma unroll
                for (int dx = 0; dx < 5; ++dx) {
                    float wv = ws[(co * 3 + ci) * 25 + dy * 5 + dx];
                    acc[co][0][0] = fmaf(wv, S[dy][dx],         acc[co][0][0]);
                    acc[co][0][1] = fmaf(wv, S[dy][dx + 1],     acc[co][0][1]);
                    acc[co][1][0] = fmaf(wv, S[dy + 1][dx],     acc[co][1][0]);
                    acc[co][1][1] = fmaf(wv, S[dy + 1][dx + 1], acc[co][1][1]);
                }
            }
        }
    }
#pragma unroll
    for (int co = 0; co < 4; ++co) {
        float v00 = leaky(acc[co][0][0]), v01 = leaky(acc[co][0][1]);
        float v10 = leaky(acc[co][1][0]), v11 = leaky(acc[co][1][1]);
        if (n >= 2) {
            float* op = c2 + ((size_t)((n - 2) * 4 + co)) * R * R + (Y0 + 2 * qy) * R + X0 + 2 * qx;
            float2 a; a.x = v00; a.y = v01; *(float2*)op = a;
            float2 b2; b2.x = v10; b2.y = v11; *(float2*)(op + R) = b2;
        }
        float pv = fmaxf(fmaxf(v00, v01), fmaxf(v10, v11));
        pout[((size_t)(n * 4 + co)) * 16384 + (16 * tileY + qy) * 128 + 16 * tileX + qx] = pv;
    }
}

// ================= Encoder body: conv5x5 pad2 + leaky + fused 2x2 maxpool ============
// Weights packed co-innermost for COG==2 (b64 per tap).
template<int R, int CI, int CO, int COG>
__device__ __forceinline__ void enc_body(
    const float* __restrict__ src1, const float* __restrict__ src2,
    const float* __restrict__ w, const float* __restrict__ bias,
    float* __restrict__ c2, float* __restrict__ pout, int bx)
{
    constexpr int W = R, H = R, Wt = R / 2;
    constexpr int RPB = 256 / Wt;
    __shared__ float ws[COG * CI * 25];
    __shared__ float pl[(RPB / 2) * COG * Wt];

    int t = threadIdx.x;
    int gid = bx * 256 + t;
    int col = gid % Wt;
    int y = (gid / Wt) % H;
    int n = (gid / (Wt * H)) & 3;
    int g = gid / (Wt * H * 4);

    if (COG == 2) {
        for (int i = t; i < COG * CI * 25; i += 256) {
            int cg = i & 1, idx = i >> 1;
            ws[idx * 2 + cg] = w[(g * COG + cg) * CI * 25 + idx];
        }
    } else {
        for (int i = t; i < COG * CI * 25; i += 256) ws[i] = w[g * COG * CI * 25 + i];
    }
    __syncthreads();

    const float* sp = (n < 2) ? (src1 + (size_t)n * CI * H * W)
                              : (src2 + (size_t)(n - 2) * CI * H * W);
    int x0 = col * 2;

    float acc[COG][2];
#pragma unroll
    for (int cg = 0; cg < COG; ++cg) { float b0 = bias[g * COG + cg]; acc[cg][0] = b0; acc[cg][1] = b0; }

    bool okr[5], okc[3];
#pragma unroll
    for (int i = 0; i < 5; ++i) { int yy = y + i - 2; okr[i] = (yy >= 0) && (yy < H); }
#pragma unroll
    for (int j = 0; j < 3; ++j) { int xx = x0 + 2 * j - 2; okc[j] = (xx >= 0) && (xx < W); }

#pragma unroll 4
    for (int ci = 0; ci < CI; ++ci) {
        const float* s = sp + ci * H * W + (y - 2) * W + (x0 - 2);
        float p[5][6];
#pragma unroll
        for (int i = 0; i < 5; ++i) {
#pragma unroll
            for (int j = 0; j < 3; ++j) {
                if (okr[i] & okc[j]) {
                    float2 v = *(const float2*)(s + i * W + 2 * j);
                    p[i][2 * j] = v.x; p[i][2 * j + 1] = v.y;
                } else { p[i][2 * j] = 0.f; p[i][2 * j + 1] = 0.f; }
            }
        }
        if (COG == 2) {
#pragma unroll
            for (int dy = 0; dy < 5; ++dy) {
#pragma unroll
                for (int dx = 0; dx < 5; ++dx) {
                    float2 wv = *(const float2*)&ws[(ci * 25 + dy * 5 + dx) * 2];
                    acc[0][0] = fmaf(wv.x, p[dy][dx],     acc[0][0]);
                    acc[0][1] = fmaf(wv.x, p[dy][dx + 1], acc[0][1]);
                    acc[1][0] = fmaf(wv.y, p[dy][dx],     acc[1][0]);
                    acc[1][1] = fmaf(wv.y, p[dy][dx + 1], acc[1][1]);
                }
            }
        } else {
#pragma unroll
            for (int cg = 0; cg < COG; ++cg) {
#pragma unroll
                for (int dy = 0; dy < 5; ++dy) {
#pragma unroll
                    for (int dx = 0; dx < 5; ++dx) {
                        float wv = ws[(cg * CI + ci) * 25 + dy * 5 + dx];
                        acc[cg][0] = fmaf(wv, p[dy][dx],     acc[cg][0]);
                        acc[cg][1] = fmaf(wv, p[dy][dx + 1], acc[cg][1]);
                    }
                }
            }
        }
    }

    int r = t / Wt;
    float m[COG];
#pragma unroll
    for (int cg = 0; cg < COG; ++cg) {
        float v0 = leaky(acc[cg][0]), v1 = leaky(acc[cg][1]);
        m[cg] = fmaxf(v0, v1);
        if (n >= 2) {
            float2 stv; stv.x = v0; stv.y = v1;
            *(float2*)(c2 + ((size_t)((n - 2) * CO + g * COG + cg)) * H * W + y * W + x0) = stv;
        }
    }
    if (r & 1) {
#pragma unroll
        for (int cg = 0; cg < COG; ++cg)
            pl[((r >> 1) * COG + cg) * Wt + col] = m[cg];
    }
    __syncthreads();
    if (!(r & 1)) {
#pragma unroll
        for (int cg = 0; cg < COG; ++cg) {
            float pv = fmaxf(m[cg], pl[((r >> 1) * COG + cg) * Wt + col]);
            pout[((size_t)(n * CO + g * COG + cg)) * Wt * Wt + (y >> 1) * Wt + col] = pv;
        }
    }
}

template<int R, int CI, int CO, int COG>
__global__ void __launch_bounds__(256) enc_k(
    const float* __restrict__ src1, const float* __restrict__ src2,
    const float* __restrict__ w, const float* __restrict__ bias,
    float* __restrict__ c2, float* __restrict__ pout)
{
    enc_body<R, CI, CO, COG>(src1, src2, w, bias, c2, pout, blockIdx.x);
}

// ================= Attention body ====================================================
template<int C, int RP, int SHIFT>
__device__ __forceinline__ void attn_body(
    const float* __restrict__ pool, const int* __restrict__ pts,
    float* __restrict__ out, int tile, int b)
{
    constexpr int P = RP * RP;
    __shared__ float qs[32 * C];
    int t = threadIdx.x;
    if (t < 32) {
        int l = t;
        int py = pts[(b * 32 + l) * 2 + 0] >> SHIFT;
        int px = pts[(b * 32 + l) * 2 + 1] >> SHIFT;
        const float* qp = pool + (size_t)(b * C) * P + py * RP + px;
        float v[C]; float s = 0.f;
#pragma unroll
        for (int c = 0; c < C; ++c) { v[c] = qp[c * P]; s += v[c] * v[c]; }
        float invn = 1.f / fmaxf(sqrtf(s), 1e-8f);
#pragma unroll
        for (int c = 0; c < C; ++c) qs[l * C + c] = v[c] * invn;
    }
    __syncthreads();
    int p = tile * 256 + t;
    const float* hp = pool + (size_t)((2 + b) * C) * P + p;
    float v[C]; float s = 0.f;
#pragma unroll
    for (int c = 0; c < C; ++c) { v[c] = hp[c * P]; s += v[c] * v[c]; }
    float invn2 = 1.f / fmaxf(sqrtf(s), 1e-8f);
#pragma unroll 4
    for (int l = 0; l < 32; ++l) {
        float d = 0.f;
#pragma unroll
        for (int c = 0; c < C; ++c) d = fmaf(v[c], qs[l * C + c], d);
        out[(size_t)(b * 32 + l) * P + p] = d * invn2;
    }
}

// ================= Parity feature-base bodies ========================================
template<int R, int CI, int CINW, int CO, int COG>
__device__ __forceinline__ void fb_body(
    const float* __restrict__ in, const float* __restrict__ w,
    const float* __restrict__ bias, float* __restrict__ fb,
    int par, int tile, int cog)
{
    constexpr int QD = R / 2;
    __shared__ float ws[COG * CI * 9];
    int t = threadIdx.x;
    for (int i = t; i < COG * CI * 9; i += 256) {
        int co = i / (CI * 9), rem = i - co * (CI * 9);
        ws[i] = w[(cog * COG + co) * CINW * 9 + (CINW - CI) * 9 + rem];
    }
    __syncthreads();
    int q = tile * 256 + t;
    int qx = q % QD, qy = q / QD;
    const float* ip = in + (size_t)par * CI * R * R;
    float acc[COG][2][2];
#pragma unroll
    for (int co = 0; co < COG; ++co) {
        float b0 = bias[cog * COG + co];
        acc[co][0][0] = b0; acc[co][0][1] = b0; acc[co][1][0] = b0; acc[co][1][1] = b0;
    }
    bool fr[4], fc[4];
#pragma unroll
    for (int i = 0; i < 4; ++i) {
        int yy = 2 * qy - 1 + i; fr[i] = (yy >= 0) && (yy < R);
        int xx = 2 * qx - 1 + i; fc[i] = (xx >= 0) && (xx < R);
    }
#pragma unroll 4
    for (int ci = 0; ci < CI; ++ci) {
        const float* bp = ip + (size_t)ci * R * R + (2 * qy - 1) * R + (2 * qx - 1);
        float F[4][4];
#pragma unroll
        for (int i = 0; i < 4; ++i)
#pragma unroll
            for (int j = 0; j < 4; ++j)
                F[i][j] = (fr[i] & fc[j]) ? bp[i * R + j] : 0.f;
#pragma unroll
        for (int co = 0; co < COG; ++co) {
#pragma unroll
            for (int dy = 0; dy < 3; ++dy) {
#pragma unroll
                for (int dx = 0; dx < 3; ++dx) {
                    float wv = ws[(co * CI + ci) * 9 + dy * 3 + dx];
                    acc[co][0][0] = fmaf(wv, F[dy][dx],         acc[co][0][0]);
                    acc[co][0][1] = fmaf(wv, F[dy][dx + 1],     acc[co][0][1]);
                    acc[co][1][0] = fmaf(wv, F[dy + 1][dx],     acc[co][1][0]);
                    acc[co][1][1] = fmaf(wv, F[dy + 1][dx + 1], acc[co][1][1]);
                }
            }
        }
    }
#pragma unroll
    for (int co = 0; co < COG; ++co) {
        float* op = fb + ((size_t)(par * CO + cog * COG + co)) * R * R + (2 * qy) * R + 2 * qx;
        float2 a; a.x = acc[co][0][0]; a.y = acc[co][0][1]; *(float2*)op = a;
        float2 b2; b2.x = acc[co][1][0]; b2.y = acc[co][1][1]; *(float2*)(op + R) = b2;
    }
}

__device__ __forceinline__ void fb0_body(
    const float* __restrict__ p3, const float* __restrict__ c2_3,
    const float* __restrict__ w, const float* __restrict__ bias,
    float* __restrict__ fb0, int par, int tile, int cog)
{
    __shared__ float ws0[4 * 33 * 9];
    int t = threadIdx.x;
    for (int i = t; i < 4 * 33 * 9; i += 256) ws0[i] = w[cog * 4 * 33 * 9 + i];
    __syncthreads();
    int px = tile * 256 + t;
    int x = px & 31, y = px >> 5;
    const float* prevp = p3 + (size_t)(2 + par) * 16 * 256;
    const float* featp = c2_3 + (size_t)par * 16 * 1024;
    float acc[4];
#pragma unroll
    for (int co = 0; co < 4; ++co) acc[co] = bias[cog * 4 + co];

    bool oky[3], okx[3];
    int py[3], pxh[3];
#pragma unroll
    for (int i = 0; i < 3; ++i) {
        int iy = y - 1 + i; oky[i] = (iy >= 0) && (iy < 32); py[i] = (iy >= 0 ? iy : 0) >> 1;
        int ix = x - 1 + i; okx[i] = (ix >= 0) && (ix < 32); pxh[i] = (ix >= 0 ? ix : 0) >> 1;
    }
#pragma unroll 4
    for (int ci = 0; ci < 16; ++ci) {
        const float* pp = prevp + ci * 256;
        float V[3][3];
#pragma unroll
        for (int i = 0; i < 3; ++i)
#pragma unroll
            for (int j = 0; j < 3; ++j)
                V[i][j] = (oky[i] & okx[j]) ? pp[py[i] * 16 + pxh[j]] : 0.f;
#pragma unroll
        for (int co = 0; co < 4; ++co) {
#pragma unroll
            for (int tap = 0; tap < 9; ++tap)
                acc[co] = fmaf(ws0[(co * 33 + ci) * 9 + tap], V[tap / 3][tap % 3], acc[co]);
        }
    }
#pragma unroll 4
    for (int cf = 0; cf < 16; ++cf) {
        const float* fp = featp + cf * 1024;
        float F[3][3];
#pragma unroll
        for (int i = 0; i < 3; ++i)
#pragma unroll
            for (int j = 0; j < 3; ++j) {
                int iy = y - 1 + i, ix = x - 1 + j;
                F[i][j] = (oky[i] & okx[j]) ? fp[iy * 32 + ix] : 0.f;
            }
#pragma unroll
        for (int co = 0; co < 4; ++co) {
#pragma unroll
            for (int tap = 0; tap < 9; ++tap)
                acc[co] = fmaf(ws0[(co * 33 + 17 + cf) * 9 + tap], F[tap / 3][tap % 3], acc[co]);
        }
    }
#pragma unroll
    for (int co = 0; co < 4; ++co)
        fb0[((size_t)(par * 16 + cog * 4 + co)) * 1024 + y * 32 + x] = acc[co];
}

// ========== bigprep: enc3 + attn levels 0-2 + fb1/fb2/fb3 in one launch =============
__global__ void __launch_bounds__(256) bigprep_k(
    const float* __restrict__ p0, const float* __restrict__ p1,
    const float* __restrict__ p2, const int* __restrict__ pts,
    const float* __restrict__ ew3, const float* __restrict__ eb3,
    float* __restrict__ c2_3, float* __restrict__ p3,
    const float* __restrict__ c2_0, const float* __restrict__ c2_1,
    const float* __restrict__ c2_2,
    const float* __restrict__ dw1, const float* __restrict__ db1,
    const float* __restrict__ dw2, const float* __restrict__ db2,
    const float* __restrict__ dw3, const float* __restrict__ db3,
    float* __restrict__ at0, float* __restrict__ at1, float* __restrict__ at2,
    float* __restrict__ fb1, float* __restrict__ fb2, float* __restrict__ fb3)
{
    int bx = blockIdx.x;
    if (bx < 128) {
        enc_body<32, 16, 16, 1>(p2, p2 + (size_t)2 * 16 * 32 * 32, ew3, eb3, c2_3, p3, bx);
    } else if (bx < 256) {
        int r = bx - 128; attn_body<4, 128, 1>(p0, pts, at0, r >> 1, r & 1);
    } else if (bx < 288) {
        int r = bx - 256; attn_body<8, 64, 2>(p1, pts, at1, r >> 1, r & 1);
    } else if (bx < 296) {
        int r = bx - 288; attn_body<16, 32, 3>(p2, pts, at2, r >> 1, r & 1);
    } else if (bx < 424) {
        int sub = bx - 296; int par = sub >> 6, tile = sub & 63;
        fb_body<256, 4, 9, 1, 1>(c2_0, dw3, db3, fb3, par, tile, 0);
    } else if (bx < 456) {
        int sub = bx - 424; int par = sub >> 4, tile = sub & 15;
        fb_body<128, 8, 17, 4, 4>(c2_1, dw2, db2, fb2, par, tile, 0);
    } else {
        int sub = bx - 456; int cog = sub & 1, tile = (sub >> 1) & 3, par = sub >> 3;
        fb_body<64, 16, 33, 8, 4>(c2_2, dw1, db1, fb1, par, tile, cog);
    }
}

// ========== prep2: attn level 3 + fb0 (need enc3 outputs) ===========================
__global__ void __launch_bounds__(256) prep2_k(
    const float* __restrict__ p3, const float* __restrict__ c2_3,
    const int* __restrict__ pts,
    const float* __restrict__ dw0, const float* __restrict__ db0,
    float* __restrict__ at3, float* __restrict__ fb0)
{
    int bx = blockIdx.x;
    if (bx < 2) {
        attn_body<16, 16, 4>(p3, pts, at3, bx >> 1, bx & 1);
    } else {
        int sub = bx - 2; int cog = sub & 3, tile = (sub >> 2) & 3, par = sub >> 4;
        fb0_body(p3, c2_3, dw0, db0, fb0, par, tile, cog);
    }
}

// ================= dec0k: out = leaky(fb0[k&1] + conv(up(at3[k]))) ===================
__global__ void __launch_bounds__(256) dec0k_k(
    const float* __restrict__ at3, const float* __restrict__ fb0,
    const float* __restrict__ w, float* __restrict__ out)
{
    __shared__ float ws4[9 * 16];
    int t = threadIdx.x;
    if (t < 144) {
        int tap = t / 16, co = t - (t / 16) * 16;
        ws4[tap * 16 + co] = w[co * 33 * 9 + 16 * 9 + tap];
    }
    __syncthreads();
    int gid = blockIdx.x;
    int k = gid >> 2, tile = gid & 3;
    int px = tile * 256 + t;
    int x = px & 31, y = px >> 5;
    int par = k & 1;
    const float* ap = at3 + (size_t)k * 256;

    float A[3][3];
#pragma unroll
    for (int i = 0; i < 3; ++i) {
        int iy = y - 1 + i; bool oy = (iy >= 0) && (iy < 32); int py = (iy >= 0 ? iy : 0) >> 1;
#pragma unroll
        for (int j = 0; j < 3; ++j) {
            int ix = x - 1 + j; bool ox = (ix >= 0) && (ix < 32); int qx = (ix >= 0 ? ix : 0) >> 1;
            A[i][j] = (oy && ox) ? ap[py * 16 + qx] : 0.f;
        }
    }
    float acc[16];
#pragma unroll
    for (int co = 0; co < 16; ++co)
        acc[co] = fb0[((size_t)(par * 16 + co)) * 1024 + y * 32 + x];
#pragma unroll
    for (int tap = 0; tap < 9; ++tap) {
        float av = A[tap / 3][tap % 3];
#pragma unroll
        for (int c4 = 0; c4 < 4; ++c4) {
            float4 wv = *(const float4*)&ws4[tap * 16 + c4 * 4];
            acc[c4 * 4 + 0] = fmaf(wv.x, av, acc[c4 * 4 + 0]);
            acc[c4 * 4 + 1] = fmaf(wv.y, av, acc[c4 * 4 + 1]);
            acc[c4 * 4 + 2] = fmaf(wv.z, av, acc[c4 * 4 + 2]);
            acc[c4 * 4 + 3] = fmaf(wv.w, av, acc[c4 * 4 + 3]);
        }
    }
#pragma unroll
    for (int co = 0; co < 16; ++co)
        out[((size_t)(k * 16 + co)) * 1024 + y * 32 + x] = leaky(acc[co]);
}

// ================= dec1k: 16x8 tile, 4 same-parity k x 2 co, half-res only ===========
__global__ void __launch_bounds__(256, 4) dec1k_k(
    const float* __restrict__ prev, const float* __restrict__ attn,
    const float* __restrict__ fb1, const float* __restrict__ w,
    float* __restrict__ out)
{
    constexpr int R = 64, CP = 16, CIN = 33, Rh = 32, CO = 8, COG = 4;
    __shared__ float ws[17 * 9 * COG];
    __shared__ float sh4[17 * 60 * 4];

    int t = threadIdx.x;
    int bz = blockIdx.y;
    int kg = bz >> 1, cog = bz & 1;
    int p = kg & 1;
    int kbase = (kg >> 1) * 8 + p;
    int tileY = blockIdx.x >> 2, tileX = blockIdx.x & 3;
    int Y0 = 8 * tileY, X0 = 16 * tileX;
    int hy0 = 4 * tileY - 1, hx0 = 8 * tileX - 1;

    for (int i = t; i < 17 * 9 * COG; i += 256) {
        int col = i & 3, idx = i >> 2;
        ws[idx * 4 + col] = w[(cog * COG + col) * CIN * 9 + idx];
    }
#pragma unroll 2
    for (int i = t; i < 17 * 60; i += 256) {
        int c = i / 60, rem = i - c * 60;
        int r = rem / 10, col = rem - r * 10;
        int gy = hy0 + r, gx = hx0 + col;
        bool ok = (gy >= 0) && (gy < Rh) && (gx >= 0) && (gx < Rh);
        int off = gy * Rh + gx;
        float4 v4; v4.x = 0.f; v4.y = 0.f; v4.z = 0.f; v4.w = 0.f;
        if (ok) {
            if (c < CP) {
                v4.x = prev[((size_t)((kbase + 0) * CP + c)) * Rh * Rh + off];
                v4.y = prev[((size_t)((kbase + 2) * CP + c)) * Rh * Rh + off];
                v4.z = prev[((size_t)((kbase + 4) * CP + c)) * Rh * Rh + off];
                v4.w = prev[((size_t)((kbase + 6) * CP + c)) * Rh * Rh + off];
            } else {
                v4.x = attn[(size_t)(kbase + 0) * Rh * Rh + off];
                v4.y = attn[(size_t)(kbase + 2) * Rh * Rh + off];
                v4.z = attn[(size_t)(kbase + 4) * Rh * Rh + off];
                v4.w = attn[(size_t)(kbase + 6) * Rh * Rh + off];
            }
        }
        *(float4*)&sh4[i * 4] = v4;
    }
    __syncthreads();

    int px = t & 127, copair = t >> 7;
    int qx = px & 15, qy = px >> 4;

    float acc[4][2];
#pragma unroll
    for (int c2 = 0; c2 < 2; ++c2) {
        float fv = fb1[((size_t)(p * CO + cog * COG + copair * 2 + c2)) * 4096 + (Y0 + qy) * R + X0 + qx];
#pragma unroll
        for (int j = 0; j < 4; ++j) acc[j][c2] = fv;
    }

    int rr[3] = {(qy + 1) >> 1, (qy + 2) >> 1, (qy + 3) >> 1};
    int cc[3] = {(qx + 1) >> 1, (qx + 2) >> 1, (qx + 3) >> 1};
    int pofs[3][3];
#pragma unroll
    for (int i = 0; i < 3; ++i)
#pragma unroll
        for (int j2 = 0; j2 < 3; ++j2)
            pofs[i][j2] = (rr[i] * 10 + cc[j2]) * 4;

#pragma unroll 4
    for (int ci = 0; ci < 17; ++ci) {
        const float* hp = &sh4[ci * 240];
        float4 P4[3][3];
#pragma unroll
        for (int i = 0; i < 3; ++i)
#pragma unroll
            for (int j2 = 0; j2 < 3; ++j2)
                P4[i][j2] = *(const float4*)&hp[pofs[i][j2]];
#pragma unroll
        for (int dy = 0; dy < 3; ++dy) {
#pragma unroll
            for (int dx = 0; dx < 3; ++dx) {
                float2 wv = *(const float2*)&ws[(ci * 9 + dy * 3 + dx) * 4 + copair * 2];
                acc[0][0] = fmaf(wv.x, P4[dy][dx].x, acc[0][0]);
                acc[1][0] = fmaf(wv.x, P4[dy][dx].y, acc[1][0]);
                acc[2][0] = fmaf(wv.x, P4[dy][dx].z, acc[2][0]);
                acc[3][0] = fmaf(wv.x, P4[dy][dx].w, acc[3][0]);
                acc[0][1] = fmaf(wv.y, P4[dy][dx].x, acc[0][1]);
                acc[1][1] = fmaf(wv.y, P4[dy][dx].y, acc[1][1]);
                acc[2][1] = fmaf(wv.y, P4[dy][dx].z, acc[2][1]);
                acc[3][1] = fmaf(wv.y, P4[dy][dx].w, acc[3][1]);
            }
        }
    }

#pragma unroll
    for (int j = 0; j < 4; ++j) {
        int k = kbase + 2 * j;
#pragma unroll
        for (int c2 = 0; c2 < 2; ++c2) {
            int co = cog * COG + copair * 2 + c2;
            out[((size_t)(k * CO + co)) * 4096 + (Y0 + qy) * R + X0 + qx] = leaky(acc[j][c2]);
        }
    }
}

// ================= dec2k/dec3k: half-res conv + fb init, 4-k blocks ==================
template<int R, int CP, int CO, int CINW, int MINW, bool DOLEAKY>
__global__ void __launch_bounds__(256, MINW) dechalf_k(
    const float* __restrict__ prev, const float* __restrict__ attn,
    const float* __restrict__ fb, const float* __restrict__ w,
    float* __restrict__ out)
{
    constexpr int Rh = R / 2, TX = R / 16;
    constexpr bool PACKW = (CO == 4);
    __shared__ float sh[4][(CP + 1) * 100];
    __shared__ float ws4[PACKW ? (CP + 1) * 9 * 4 : 4];

    int t = threadIdx.x;
    int kg = blockIdx.y;
    int p = kg & 1;
    int kbase = (kg >> 1) * 8 + p;
    int tileY = blockIdx.x / TX, tileX = blockIdx.x % TX;
    int Y0 = 16 * tileY, X0 = 16 * tileX;
    int hy0 = 8 * tileY - 1, hx0 = 8 * tileX - 1;

    if (PACKW) {
        for (int i = t; i < (CP + 1) * 9 * 4; i += 256) {
            int co = i & 3, idx = i >> 2;
            ws4[i] = w[co * CINW * 9 + idx];
        }
    }
#pragma unroll 2
    for (int i = t; i < CP * 100; i += 256) {
        int c = i / 100, rem = i - c * 100;
        int r = rem / 10, col = rem - r * 10;
        int gy = hy0 + r, gx = hx0 + col;
        bool ok = (gy >= 0) && (gy < Rh) && (gx >= 0) && (gx < Rh);
        int off = gy * Rh + gx;
#pragma unroll
        for (int j = 0; j < 4; ++j) {
            float v = 0.f;
            if (ok) v = prev[((size_t)((kbase + 2 * j) * CP + c)) * Rh * Rh + off];
            sh[j][i] = v;
        }
    }
    if (t < 100) {
        int r = t / 10, col = t - r * 10;
        int gy = hy0 + r, gx = hx0 + col;
        bool ok = (gy >= 0) && (gy < Rh) && (gx >= 0) && (gx < Rh);
        int off = gy * Rh + gx;
#pragma unroll
        for (int j = 0; j < 4; ++j) {
            float v = 0.f;
            if (ok) v = attn[(size_t)(kbase + 2 * j) * Rh * Rh + off];
            sh[j][CP * 100 + t] = v;
        }
    }
    __syncthreads();

    int ksub = t >> 6, q = t & 63, qx = q & 7, qy = q >> 3;
    int k = kbase + 2 * ksub;

    float acc[CO][2][2];
#pragma unroll
    for (int co = 0; co < CO; ++co) {
        const float* fp = fb + ((size_t)(p * CO + co)) * R * R + (Y0 + 2 * qy) * R + X0 + 2 * qx;
        float2 r0 = *(const float2*)fp;
        float2 r1 = *(const float2*)(fp + R);
        acc[co][0][0] = r0.x; acc[co][0][1] = r0.y;
        acc[co][1][0] = r1.x; acc[co][1][1] = r1.y;
    }

#pragma unroll
    for (int ci = 0; ci < CP + 1; ++ci) {
        const float* hp = &sh[ksub][ci * 100 + qy * 10 + qx];
        float P[3][3];
#pragma unroll
        for (int i = 0; i < 3; ++i)
#pragma unroll
            for (int j = 0; j < 3; ++j) P[i][j] = hp[i * 10 + j];
#pragma unroll
        for (int dy = 0; dy < 3; ++dy) {
#pragma unroll
            for (int dx = 0; dx < 3; ++dx) {
                float p00 = P[(dy + 1) >> 1][(dx + 1) >> 1];
                float p01 = P[(dy + 1) >> 1][(dx + 2) >> 1];
                float p10 = P[(dy + 2) >> 1][(dx + 1) >> 1];
                float p11 = P[(dy + 2) >> 1][(dx + 2) >> 1];
                if (PACKW) {
                    float4 wv = *(const float4*)&ws4[(ci * 9 + dy * 3 + dx) * 4];
                    const float* wvp = (const float*)&wv;
#pragma unroll
                    for (int co = 0; co < CO; ++co) {
                        acc[co][0][0] = fmaf(wvp[co], p00, acc[co][0][0]);
                        acc[co][0][1] = fmaf(wvp[co], p01, acc[co][0][1]);
                        acc[co][1][0] = fmaf(wvp[co], p10, acc[co][1][0]);
                        acc[co][1][1] = fmaf(wvp[co], p11, acc[co][1][1]);
                    }
                } else {
                    float wv = w[ci * 9 + dy * 3 + dx];
                    acc[0][0][0] = fmaf(wv, p00, acc[0][0][0]);
                    acc[0][0][1] = fmaf(wv, p01, acc[0][0][1]);
                    acc[0][1][0] = fmaf(wv, p10, acc[0][1][0]);
                    acc[0][1][1] = fmaf(wv, p11, acc[0][1][1]);
                }
            }
        }
    }

#pragma unroll
    for (int co = 0; co < CO; ++co) {
        float v00 = acc[co][0][0], v01 = acc[co][0][1];
        float v10 = acc[co][1][0], v11 = acc[co][1][1];
        if (DOLEAKY) { v00 = leaky(v00); v01 = leaky(v01); v10 = leaky(v10); v11 = leaky(v11); }
        float* op = out + ((size_t)(k * CO + co)) * R * R + (Y0 + 2 * qy) * R + X0 + 2 * qx;
        float2 a; a.x = v00; a.y = v01; *(float2*)op = a;
        float2 b2; b2.x = v10; b2.y = v11; *(float2*)(op + R) = b2;
    }
}

extern "C" void kernel_launch(void* const* d_in, const int* in_sizes, int n_in,
                              void* d_out, int out_size, void* d_ws, size_t ws_size,
                              hipStream_t stream)
{
    (void)in_sizes; (void)n_in; (void)out_size; (void)ws_size;
    const float* x1 = (const float*)d_in[0];
    const float* x2 = (const float*)d_in[1];
    const int* pts = (const int*)d_in[2];
    const float* ew[4] = {(const float*)d_in[3], (const float*)d_in[5],
                          (const float*)d_in[7], (const float*)d_in[9]};
    const float* eb[4] = {(const float*)d_in[4], (const float*)d_in[6],
                          (const float*)d_in[8], (const float*)d_in[10]};
    const float* dw[4] = {(const float*)d_in[11], (const float*)d_in[13],
                          (const float*)d_in[15], (const float*)d_in[17]};
    const float* db[4] = {(const float*)d_in[12], (const float*)d_in[14],
                          (const float*)d_in[16], (const float*)d_in[18]};

    float* wsp = (float*)d_ws;
    size_t off = 0;
    auto A = [&](size_t n) { float* p = wsp + off; off += n; return p; };

    float* p0 = A((size_t)4 * 4 * 128 * 128);
    float* p1 = A((size_t)4 * 8 * 64 * 64);
    float* p2 = A((size_t)4 * 16 * 32 * 32);
    float* p3 = A((size_t)4 * 16 * 16 * 16);
    float* c2_0 = A((size_t)2 * 4 * 256 * 256);
    float* c2_1 = A((size_t)2 * 8 * 128 * 128);
    float* c2_2 = A((size_t)2 * 16 * 64 * 64);
    float* c2_3 = A((size_t)2 * 16 * 32 * 32);
    float* at0 = A((size_t)64 * 128 * 128);
    float* at1 = A((size_t)64 * 64 * 64);
    float* at2 = A((size_t)64 * 32 * 32);
    float* at3 = A((size_t)64 * 16 * 16);
    float* dec0 = A((size_t)64 * 16 * 32 * 32);
    float* dec1 = A((size_t)64 * 8 * 64 * 64);
    float* dec2 = A((size_t)64 * 4 * 128 * 128);
    float* fb0 = A((size_t)2 * 16 * 32 * 32);
    float* fb1 = A((size_t)2 * 8 * 64 * 64);
    float* fb2 = A((size_t)2 * 4 * 128 * 128);
    float* fb3 = A((size_t)2 * 256 * 256);
    float* outp = (float*)d_out;

    // ---- Encoder levels 0-2 ----
    { dim3 g(64, 4); enc0_k<<<g, 256, 0, stream>>>(x1, x2, ew[0], eb[0], c2_0, p0); }
    enc_k<128, 4, 8, 2><<<512, 256, 0, stream>>>(p0, p0 + (size_t)2 * 4 * 128 * 128,
                                                 ew[1], eb[1], c2_1, p1);
    enc_k<64, 8, 16, 2><<<256, 256, 0, stream>>>(p1, p1 + (size_t)2 * 8 * 64 * 64,
                                                 ew[2], eb[2], c2_2, p2);

    // ---- bigprep: enc3 + attn levels 0-2 + fb1/fb2/fb3 ----
    bigprep_k<<<472, 256, 0, stream>>>(p0, p1, p2, pts, ew[3], eb[3], c2_3, p3,
                                       c2_0, c2_1, c2_2,
                                       dw[1], db[1], dw[2], db[2], dw[3], db[3],
                                       at0, at1, at2, fb1, fb2, fb3);

    // ---- prep2: attn3 + fb0 ----
    prep2_k<<<34, 256, 0, stream>>>(p3, c2_3, pts, dw[0], db[0], at3, fb0);

    // ---- Per-k decoder ----
    dec0k_k<<<256, 256, 0, stream>>>(at3, fb0, dw[0], dec0);
    { dim3 g(32, 32); dec1k_k<<<g, 256, 0, stream>>>(dec0, at2, fb1, dw[1], dec1); }
    { dim3 g(64, 16); dechalf_k<128, 8, 4, 17, 4, true><<<g, 256, 0, stream>>>(dec1, at1, fb2, dw[2], dec2); }
    { dim3 g(256, 16); dechalf_k<256, 4, 1, 9, 5, false><<<g, 256, 0, stream>>>(dec2, at0, fb3, dw[3], outp); }
}

// Round 19
// 125.761 us; speedup vs baseline: 1.1119x; 1.0404x over previous
//
#include <hip/hip_runtime.h>
#include <cstdint>

__device__ __forceinline__ float leaky(float v) { return v >= 0.f ? v : 0.01f * v; }

// ================= Encoder level 0: staged conv5x5 + leaky + pool ====================
__global__ void __launch_bounds__(256) enc0_k(
    const float* __restrict__ x1, const float* __restrict__ x2,
    const float* __restrict__ w, const float* __restrict__ bias,
    float* __restrict__ c2, float* __restrict__ pout)
{
    constexpr int R = 256;
    __shared__ float ss[3 * 36 * 36];
    __shared__ float ws[4 * 3 * 25 + 4];
    int t = threadIdx.x;
    int n = blockIdx.y;
    int tileY = blockIdx.x >> 3, tileX = blockIdx.x & 7;
    int Y0 = 32 * tileY, X0 = 32 * tileX;
    const float* src = (n < 2) ? x1 + (size_t)n * 3 * R * R
                               : x2 + (size_t)(n - 2) * 3 * R * R;

    for (int i = t; i < 300; i += 256) ws[i] = w[i];
    if (t < 4) ws[300 + t] = bias[t];
    for (int ci = 0; ci < 3; ++ci) {
        const float* sp = src + (size_t)ci * R * R;
        for (int i = t; i < 1296; i += 256) {
            int r = i / 36, col = i - r * 36;
            int gy = Y0 - 2 + r, gx = X0 - 2 + col;
            float v = 0.f;
            if (gy >= 0 && gy < R && gx >= 0 && gx < R) v = sp[gy * R + gx];
            ss[ci * 1296 + i] = v;
        }
    }
    __syncthreads();

    int qx = t & 15, qy = t >> 4;
    float acc[4][2][2];
#pragma unroll
    for (int co = 0; co < 4; ++co) {
        float b0 = ws[300 + co];
        acc[co][0][0] = b0; acc[co][0][1] = b0; acc[co][1][0] = b0; acc[co][1][1] = b0;
    }
#pragma unroll
    for (int ci = 0; ci < 3; ++ci) {
        const float* sp = &ss[ci * 1296 + (2 * qy) * 36 + 2 * qx];
        float S[6][6];
#pragma unroll
        for (int i = 0; i < 6; ++i)
#pragma unroll
            for (int j = 0; j < 6; ++j) S[i][j] = sp[i * 36 + j];
#pragma unroll
        for (int co = 0; co < 4; ++co) {
#pragma unroll
            for (int dy = 0; dy < 5; ++dy) {
#pragma unroll
                for (int dx = 0; dx < 5; ++dx) {
                    float wv = ws[(co * 3 + ci) * 25 + dy * 5 + dx];
                    acc[co][0][0] = fmaf(wv, S[dy][dx],         acc[co][0][0]);
                    acc[co][0][1] = fmaf(wv, S[dy][dx + 1],     acc[co][0][1]);
                    acc[co][1][0] = fmaf(wv, S[dy + 1][dx],     acc[co][1][0]);
                    acc[co][1][1] = fmaf(wv, S[dy + 1][dx + 1], acc[co][1][1]);
                }
            }
        }
    }
#pragma unroll
    for (int co = 0; co < 4; ++co) {
        float v00 = leaky(acc[co][0][0]), v01 = leaky(acc[co][0][1]);
        float v10 = leaky(acc[co][1][0]), v11 = leaky(acc[co][1][1]);
        if (n >= 2) {
            float* op = c2 + ((size_t)((n - 2) * 4 + co)) * R * R + (Y0 + 2 * qy) * R + X0 + 2 * qx;
            float2 a; a.x = v00; a.y = v01; *(float2*)op = a;
            float2 b2; b2.x = v10; b2.y = v11; *(float2*)(op + R) = b2;
        }
        float pv = fmaxf(fmaxf(v00, v01), fmaxf(v10, v11));
        pout[((size_t)(n * 4 + co)) * 16384 + (16 * tileY + qy) * 128 + 16 * tileX + qx] = pv;
    }
}

// ================= Encoder body: conv5x5 pad2 + leaky + fused 2x2 maxpool ============
template<int R, int CI, int CO, int COG>
__device__ __forceinline__ void enc_body(
    const float* __restrict__ src1, const float* __restrict__ src2,
    const float* __restrict__ w, const float* __restrict__ bias,
    float* __restrict__ c2, float* __restrict__ pout, int bx)
{
    constexpr int W = R, H = R, Wt = R / 2;
    constexpr int RPB = 256 / Wt;
    __shared__ float ws[COG * CI * 25];
    __shared__ float pl[(RPB / 2) * COG * Wt];

    int t = threadIdx.x;
    int gid = bx * 256 + t;
    int col = gid % Wt;
    int y = (gid / Wt) % H;
    int n = (gid / (Wt * H)) & 3;
    int g = gid / (Wt * H * 4);

    if (COG == 2) {
        for (int i = t; i < COG * CI * 25; i += 256) {
            int cg = i & 1, idx = i >> 1;
            ws[idx * 2 + cg] = w[(g * COG + cg) * CI * 25 + idx];
        }
    } else {
        for (int i = t; i < COG * CI * 25; i += 256) ws[i] = w[g * COG * CI * 25 + i];
    }
    __syncthreads();

    const float* sp = (n < 2) ? (src1 + (size_t)n * CI * H * W)
                              : (src2 + (size_t)(n - 2) * CI * H * W);
    int x0 = col * 2;

    float acc[COG][2];
#pragma unroll
    for (int cg = 0; cg < COG; ++cg) { float b0 = bias[g * COG + cg]; acc[cg][0] = b0; acc[cg][1] = b0; }

    bool okr[5], okc[3];
#pragma unroll
    for (int i = 0; i < 5; ++i) { int yy = y + i - 2; okr[i] = (yy >= 0) && (yy < H); }
#pragma unroll
    for (int j = 0; j < 3; ++j) { int xx = x0 + 2 * j - 2; okc[j] = (xx >= 0) && (xx < W); }

#pragma unroll 4
    for (int ci = 0; ci < CI; ++ci) {
        const float* s = sp + ci * H * W + (y - 2) * W + (x0 - 2);
        float p[5][6];
#pragma unroll
        for (int i = 0; i < 5; ++i) {
#pragma unroll
            for (int j = 0; j < 3; ++j) {
                if (okr[i] & okc[j]) {
                    float2 v = *(const float2*)(s + i * W + 2 * j);
                    p[i][2 * j] = v.x; p[i][2 * j + 1] = v.y;
                } else { p[i][2 * j] = 0.f; p[i][2 * j + 1] = 0.f; }
            }
        }
        if (COG == 2) {
#pragma unroll
            for (int dy = 0; dy < 5; ++dy) {
#pragma unroll
                for (int dx = 0; dx < 5; ++dx) {
                    float2 wv = *(const float2*)&ws[(ci * 25 + dy * 5 + dx) * 2];
                    acc[0][0] = fmaf(wv.x, p[dy][dx],     acc[0][0]);
                    acc[0][1] = fmaf(wv.x, p[dy][dx + 1], acc[0][1]);
                    acc[1][0] = fmaf(wv.y, p[dy][dx],     acc[1][0]);
                    acc[1][1] = fmaf(wv.y, p[dy][dx + 1], acc[1][1]);
                }
            }
        } else {
#pragma unroll
            for (int cg = 0; cg < COG; ++cg) {
#pragma unroll
                for (int dy = 0; dy < 5; ++dy) {
#pragma unroll
                    for (int dx = 0; dx < 5; ++dx) {
                        float wv = ws[(cg * CI + ci) * 25 + dy * 5 + dx];
                        acc[cg][0] = fmaf(wv, p[dy][dx],     acc[cg][0]);
                        acc[cg][1] = fmaf(wv, p[dy][dx + 1], acc[cg][1]);
                    }
                }
            }
        }
    }

    int r = t / Wt;
    float m[COG];
#pragma unroll
    for (int cg = 0; cg < COG; ++cg) {
        float v0 = leaky(acc[cg][0]), v1 = leaky(acc[cg][1]);
        m[cg] = fmaxf(v0, v1);
        if (n >= 2) {
            float2 stv; stv.x = v0; stv.y = v1;
            *(float2*)(c2 + ((size_t)((n - 2) * CO + g * COG + cg)) * H * W + y * W + x0) = stv;
        }
    }
    if (r & 1) {
#pragma unroll
        for (int cg = 0; cg < COG; ++cg)
            pl[((r >> 1) * COG + cg) * Wt + col] = m[cg];
    }
    __syncthreads();
    if (!(r & 1)) {
#pragma unroll
        for (int cg = 0; cg < COG; ++cg) {
            float pv = fmaxf(m[cg], pl[((r >> 1) * COG + cg) * Wt + col]);
            pout[((size_t)(n * CO + g * COG + cg)) * Wt * Wt + (y >> 1) * Wt + col] = pv;
        }
    }
}

template<int R, int CI, int CO, int COG>
__global__ void __launch_bounds__(256) enc_k(
    const float* __restrict__ src1, const float* __restrict__ src2,
    const float* __restrict__ w, const float* __restrict__ bias,
    float* __restrict__ c2, float* __restrict__ pout)
{
    enc_body<R, CI, CO, COG>(src1, src2, w, bias, c2, pout, blockIdx.x);
}

// ================= Attention body ====================================================
template<int C, int RP, int SHIFT>
__device__ __forceinline__ void attn_body(
    const float* __restrict__ pool, const int* __restrict__ pts,
    float* __restrict__ out, int tile, int b)
{
    constexpr int P = RP * RP;
    __shared__ float qs[32 * C];
    int t = threadIdx.x;
    if (t < 32) {
        int l = t;
        int py = pts[(b * 32 + l) * 2 + 0] >> SHIFT;
        int px = pts[(b * 32 + l) * 2 + 1] >> SHIFT;
        const float* qp = pool + (size_t)(b * C) * P + py * RP + px;
        float v[C]; float s = 0.f;
#pragma unroll
        for (int c = 0; c < C; ++c) { v[c] = qp[c * P]; s += v[c] * v[c]; }
        float invn = 1.f / fmaxf(sqrtf(s), 1e-8f);
#pragma unroll
        for (int c = 0; c < C; ++c) qs[l * C + c] = v[c] * invn;
    }
    __syncthreads();
    int p = tile * 256 + t;
    const float* hp = pool + (size_t)((2 + b) * C) * P + p;
    float v[C]; float s = 0.f;
#pragma unroll
    for (int c = 0; c < C; ++c) { v[c] = hp[c * P]; s += v[c] * v[c]; }
    float invn2 = 1.f / fmaxf(sqrtf(s), 1e-8f);
#pragma unroll 4
    for (int l = 0; l < 32; ++l) {
        float d = 0.f;
#pragma unroll
        for (int c = 0; c < C; ++c) d = fmaf(v[c], qs[l * C + c], d);
        out[(size_t)(b * 32 + l) * P + p] = d * invn2;
    }
}

// ================= Parity feature-base bodies ========================================
template<int R, int CI, int CINW, int CO, int COG>
__device__ __forceinline__ void fb_body(
    const float* __restrict__ in, const float* __restrict__ w,
    const float* __restrict__ bias, float* __restrict__ fb,
    int par, int tile, int cog)
{
    constexpr int QD = R / 2;
    __shared__ float ws[COG * CI * 9];
    int t = threadIdx.x;
    for (int i = t; i < COG * CI * 9; i += 256) {
        int co = i / (CI * 9), rem = i - co * (CI * 9);
        ws[i] = w[(cog * COG + co) * CINW * 9 + (CINW - CI) * 9 + rem];
    }
    __syncthreads();
    int q = tile * 256 + t;
    int qx = q % QD, qy = q / QD;
    const float* ip = in + (size_t)par * CI * R * R;
    float acc[COG][2][2];
#pragma unroll
    for (int co = 0; co < COG; ++co) {
        float b0 = bias[cog * COG + co];
        acc[co][0][0] = b0; acc[co][0][1] = b0; acc[co][1][0] = b0; acc[co][1][1] = b0;
    }
    bool fr[4], fc[4];
#pragma unroll
    for (int i = 0; i < 4; ++i) {
        int yy = 2 * qy - 1 + i; fr[i] = (yy >= 0) && (yy < R);
        int xx = 2 * qx - 1 + i; fc[i] = (xx >= 0) && (xx < R);
    }
#pragma unroll 4
    for (int ci = 0; ci < CI; ++ci) {
        const float* bp = ip + (size_t)ci * R * R + (2 * qy - 1) * R + (2 * qx - 1);
        float F[4][4];
#pragma unroll
        for (int i = 0; i < 4; ++i)
#pragma unroll
            for (int j = 0; j < 4; ++j)
                F[i][j] = (fr[i] & fc[j]) ? bp[i * R + j] : 0.f;
#pragma unroll
        for (int co = 0; co < COG; ++co) {
#pragma unroll
            for (int dy = 0; dy < 3; ++dy) {
#pragma unroll
                for (int dx = 0; dx < 3; ++dx) {
                    float wv = ws[(co * CI + ci) * 9 + dy * 3 + dx];
                    acc[co][0][0] = fmaf(wv, F[dy][dx],         acc[co][0][0]);
                    acc[co][0][1] = fmaf(wv, F[dy][dx + 1],     acc[co][0][1]);
                    acc[co][1][0] = fmaf(wv, F[dy + 1][dx],     acc[co][1][0]);
                    acc[co][1][1] = fmaf(wv, F[dy + 1][dx + 1], acc[co][1][1]);
                }
            }
        }
    }
#pragma unroll
    for (int co = 0; co < COG; ++co) {
        float* op = fb + ((size_t)(par * CO + cog * COG + co)) * R * R + (2 * qy) * R + 2 * qx;
        float2 a; a.x = acc[co][0][0]; a.y = acc[co][0][1]; *(float2*)op = a;
        float2 b2; b2.x = acc[co][1][0]; b2.y = acc[co][1][1]; *(float2*)(op + R) = b2;
    }
}

__device__ __forceinline__ void fb0_body(
    const float* __restrict__ p3, const float* __restrict__ c2_3,
    const float* __restrict__ w, const float* __restrict__ bias,
    float* __restrict__ fb0, int par, int tile, int cog)
{
    __shared__ float ws0[4 * 33 * 9];
    int t = threadIdx.x;
    for (int i = t; i < 4 * 33 * 9; i += 256) ws0[i] = w[cog * 4 * 33 * 9 + i];
    __syncthreads();
    int px = tile * 256 + t;
    int x = px & 31, y = px >> 5;
    const float* prevp = p3 + (size_t)(2 + par) * 16 * 256;
    const float* featp = c2_3 + (size_t)par * 16 * 1024;
    float acc[4];
#pragma unroll
    for (int co = 0; co < 4; ++co) acc[co] = bias[cog * 4 + co];

    bool oky[3], okx[3];
    int py[3], pxh[3];
#pragma unroll
    for (int i = 0; i < 3; ++i) {
        int iy = y - 1 + i; oky[i] = (iy >= 0) && (iy < 32); py[i] = (iy >= 0 ? iy : 0) >> 1;
        int ix = x - 1 + i; okx[i] = (ix >= 0) && (ix < 32); pxh[i] = (ix >= 0 ? ix : 0) >> 1;
    }
#pragma unroll 4
    for (int ci = 0; ci < 16; ++ci) {
        const float* pp = prevp + ci * 256;
        float V[3][3];
#pragma unroll
        for (int i = 0; i < 3; ++i)
#pragma unroll
            for (int j = 0; j < 3; ++j)
                V[i][j] = (oky[i] & okx[j]) ? pp[py[i] * 16 + pxh[j]] : 0.f;
#pragma unroll
        for (int co = 0; co < 4; ++co) {
#pragma unroll
            for (int tap = 0; tap < 9; ++tap)
                acc[co] = fmaf(ws0[(co * 33 + ci) * 9 + tap], V[tap / 3][tap % 3], acc[co]);
        }
    }
#pragma unroll 4
    for (int cf = 0; cf < 16; ++cf) {
        const float* fp = featp + cf * 1024;
        float F[3][3];
#pragma unroll
        for (int i = 0; i < 3; ++i)
#pragma unroll
            for (int j = 0; j < 3; ++j) {
                int iy = y - 1 + i, ix = x - 1 + j;
                F[i][j] = (oky[i] & okx[j]) ? fp[iy * 32 + ix] : 0.f;
            }
#pragma unroll
        for (int co = 0; co < 4; ++co) {
#pragma unroll
            for (int tap = 0; tap < 9; ++tap)
                acc[co] = fmaf(ws0[(co * 33 + 17 + cf) * 9 + tap], F[tap / 3][tap % 3], acc[co]);
        }
    }
#pragma unroll
    for (int co = 0; co < 4; ++co)
        fb0[((size_t)(par * 16 + cog * 4 + co)) * 1024 + y * 32 + x] = acc[co];
}

// ========== bigprep: enc3 + attn levels 0-2 + fb1/fb2/fb3 in one launch =============
__global__ void __launch_bounds__(256) bigprep_k(
    const float* __restrict__ p0, const float* __restrict__ p1,
    const float* __restrict__ p2, const int* __restrict__ pts,
    const float* __restrict__ ew3, const float* __restrict__ eb3,
    float* __restrict__ c2_3, float* __restrict__ p3,
    const float* __restrict__ c2_0, const float* __restrict__ c2_1,
    const float* __restrict__ c2_2,
    const float* __restrict__ dw1, const float* __restrict__ db1,
    const float* __restrict__ dw2, const float* __restrict__ db2,
    const float* __restrict__ dw3, const float* __restrict__ db3,
    float* __restrict__ at0, float* __restrict__ at1, float* __restrict__ at2,
    float* __restrict__ fb1, float* __restrict__ fb2, float* __restrict__ fb3)
{
    int bx = blockIdx.x;
    if (bx < 128) {
        enc_body<32, 16, 16, 1>(p2, p2 + (size_t)2 * 16 * 32 * 32, ew3, eb3, c2_3, p3, bx);
    } else if (bx < 256) {
        int r = bx - 128; attn_body<4, 128, 1>(p0, pts, at0, r >> 1, r & 1);
    } else if (bx < 288) {
        int r = bx - 256; attn_body<8, 64, 2>(p1, pts, at1, r >> 1, r & 1);
    } else if (bx < 296) {
        int r = bx - 288; attn_body<16, 32, 3>(p2, pts, at2, r >> 1, r & 1);
    } else if (bx < 424) {
        int sub = bx - 296; int par = sub >> 6, tile = sub & 63;
        fb_body<256, 4, 9, 1, 1>(c2_0, dw3, db3, fb3, par, tile, 0);
    } else if (bx < 456) {
        int sub = bx - 424; int par = sub >> 4, tile = sub & 15;
        fb_body<128, 8, 17, 4, 4>(c2_1, dw2, db2, fb2, par, tile, 0);
    } else {
        int sub = bx - 456; int cog = sub & 1, tile = (sub >> 1) & 3, par = sub >> 3;
        fb_body<64, 16, 33, 8, 4>(c2_2, dw1, db1, fb1, par, tile, cog);
    }
}

// ========== prep2: attn level 3 + fb0 (need enc3 outputs) ===========================
__global__ void __launch_bounds__(256) prep2_k(
    const float* __restrict__ p3, const float* __restrict__ c2_3,
    const int* __restrict__ pts,
    const float* __restrict__ dw0, const float* __restrict__ db0,
    float* __restrict__ at3, float* __restrict__ fb0)
{
    int bx = blockIdx.x;
    if (bx < 2) {
        attn_body<16, 16, 4>(p3, pts, at3, bx >> 1, bx & 1);
    } else {
        int sub = bx - 2; int cog = sub & 3, tile = (sub >> 2) & 3, par = sub >> 4;
        fb0_body(p3, c2_3, dw0, db0, fb0, par, tile, cog);
    }
}

// ================= dec0k: out = leaky(fb0[k&1] + conv(up(at3[k]))) ===================
__global__ void __launch_bounds__(256) dec0k_k(
    const float* __restrict__ at3, const float* __restrict__ fb0,
    const float* __restrict__ w, float* __restrict__ out)
{
    __shared__ float ws4[9 * 16];
    int t = threadIdx.x;
    if (t < 144) {
        int tap = t / 16, co = t - (t / 16) * 16;
        ws4[tap * 16 + co] = w[co * 33 * 9 + 16 * 9 + tap];
    }
    __syncthreads();
    int gid = blockIdx.x;
    int k = gid >> 2, tile = gid & 3;
    int px = tile * 256 + t;
    int x = px & 31, y = px >> 5;
    int par = k & 1;
    const float* ap = at3 + (size_t)k * 256;

    float A[3][3];
#pragma unroll
    for (int i = 0; i < 3; ++i) {
        int iy = y - 1 + i; bool oy = (iy >= 0) && (iy < 32); int py = (iy >= 0 ? iy : 0) >> 1;
#pragma unroll
        for (int j = 0; j < 3; ++j) {
            int ix = x - 1 + j; bool ox = (ix >= 0) && (ix < 32); int qx = (ix >= 0 ? ix : 0) >> 1;
            A[i][j] = (oy && ox) ? ap[py * 16 + qx] : 0.f;
        }
    }
    float acc[16];
#pragma unroll
    for (int co = 0; co < 16; ++co)
        acc[co] = fb0[((size_t)(par * 16 + co)) * 1024 + y * 32 + x];
#pragma unroll
    for (int tap = 0; tap < 9; ++tap) {
        float av = A[tap / 3][tap % 3];
#pragma unroll
        for (int c4 = 0; c4 < 4; ++c4) {
            float4 wv = *(const float4*)&ws4[tap * 16 + c4 * 4];
            acc[c4 * 4 + 0] = fmaf(wv.x, av, acc[c4 * 4 + 0]);
            acc[c4 * 4 + 1] = fmaf(wv.y, av, acc[c4 * 4 + 1]);
            acc[c4 * 4 + 2] = fmaf(wv.z, av, acc[c4 * 4 + 2]);
            acc[c4 * 4 + 3] = fmaf(wv.w, av, acc[c4 * 4 + 3]);
        }
    }
#pragma unroll
    for (int co = 0; co < 16; ++co)
        out[((size_t)(k * 16 + co)) * 1024 + y * 32 + x] = leaky(acc[co]);
}

// ========= parity-group helper: combined 2x2 weights from 3x3 upsample conv =========
__device__ __forceinline__ float parity_wsum(const float* wp, int py, int pxr, int ti, int tj)
{
    int dy0 = (py == 0) ? (ti == 0 ? 0 : 1) : (ti == 0 ? 0 : 2);
    int dy1 = (py == 0) ? (ti == 0 ? 0 : 2) : (ti == 0 ? 1 : 2);
    int dx0 = (pxr == 0) ? (tj == 0 ? 0 : 1) : (tj == 0 ? 0 : 2);
    int dx1 = (pxr == 0) ? (tj == 0 ? 0 : 2) : (tj == 0 ? 1 : 2);
    float s = 0.f;
    for (int dy = dy0; dy <= dy1; ++dy)
        for (int dx = dx0; dx <= dx1; ++dx) s += wp[dy * 3 + dx];
    return s;
}

// ============ dec1k: parity 2x2 conv, 16x8 tile, 4 same-parity k x 2 co =============
__global__ void __launch_bounds__(256, 4) dec1k_k(
    const float* __restrict__ prev, const float* __restrict__ attn,
    const float* __restrict__ fb1, const float* __restrict__ w,
    float* __restrict__ out)
{
    constexpr int R = 64, CP = 16, CIN = 33, Rh = 32, CO = 8, COG = 4, NCI = 17;
    __shared__ float wc[NCI * 16 * COG];          // ((ci*4+par)*4+tap)*4+co
    __shared__ float sh4[NCI * 60 * 4];

    int t = threadIdx.x;
    int bz = blockIdx.y;
    int kg = bz >> 1, cog = bz & 1;
    int p = kg & 1;
    int kbase = (kg >> 1) * 8 + p;
    int tileY = blockIdx.x >> 2, tileX = blockIdx.x & 3;
    int Y0 = 8 * tileY, X0 = 16 * tileX;
    int hy0 = 4 * tileY - 1, hx0 = 8 * tileX - 1;

    for (int i = t; i < NCI * 16 * COG; i += 256) {
        int co = i & 3, tap = (i >> 2) & 3, par = (i >> 4) & 3, ci = i >> 6;
        const float* wp = &w[(cog * COG + co) * CIN * 9 + ci * 9];
        wc[i] = parity_wsum(wp, par >> 1, par & 1, tap >> 1, tap & 1);
    }
#pragma unroll 2
    for (int i = t; i < NCI * 60; i += 256) {
        int c = i / 60, rem = i - c * 60;
        int r = rem / 10, col = rem - r * 10;
        int gy = hy0 + r, gx = hx0 + col;
        bool ok = (gy >= 0) && (gy < Rh) && (gx >= 0) && (gx < Rh);
        int off = gy * Rh + gx;
        float4 v4; v4.x = 0.f; v4.y = 0.f; v4.z = 0.f; v4.w = 0.f;
        if (ok) {
            if (c < CP) {
                v4.x = prev[((size_t)((kbase + 0) * CP + c)) * Rh * Rh + off];
                v4.y = prev[((size_t)((kbase + 2) * CP + c)) * Rh * Rh + off];
                v4.z = prev[((size_t)((kbase + 4) * CP + c)) * Rh * Rh + off];
                v4.w = prev[((size_t)((kbase + 6) * CP + c)) * Rh * Rh + off];
            } else {
                v4.x = attn[(size_t)(kbase + 0) * Rh * Rh + off];
                v4.y = attn[(size_t)(kbase + 2) * Rh * Rh + off];
                v4.z = attn[(size_t)(kbase + 4) * Rh * Rh + off];
                v4.w = attn[(size_t)(kbase + 6) * Rh * Rh + off];
            }
        }
        *(float4*)&sh4[i * 4] = v4;
    }
    __syncthreads();

    int px = t & 127, copair = t >> 7;
    int qx = px & 15, qy = px >> 4;
    int par = (qy & 1) * 2 + (qx & 1);
    int rb = (qy + 1) >> 1, cb = (qx + 1) >> 1;
    int o00 = (rb * 10 + cb) * 4;

    float acc[4][2];
#pragma unroll
    for (int c2 = 0; c2 < 2; ++c2) {
        float fv = fb1[((size_t)(p * CO + cog * COG + copair * 2 + c2)) * 4096 + (Y0 + qy) * R + X0 + qx];
#pragma unroll
        for (int j = 0; j < 4; ++j) acc[j][c2] = fv;
    }

#pragma unroll 4
    for (int ci = 0; ci < NCI; ++ci) {
        const float* hp = &sh4[ci * 240];
        float4 P00 = *(const float4*)&hp[o00];
        float4 P01 = *(const float4*)&hp[o00 + 4];
        float4 P10 = *(const float4*)&hp[o00 + 40];
        float4 P11 = *(const float4*)&hp[o00 + 44];
        const float* wb = &wc[(ci * 4 + par) * 16 + copair * 2];
        float2 w0 = *(const float2*)&wb[0];
        float2 w1 = *(const float2*)&wb[4];
        float2 w2 = *(const float2*)&wb[8];
        float2 w3 = *(const float2*)&wb[12];
        acc[0][0] = fmaf(w0.x, P00.x, acc[0][0]); acc[0][0] = fmaf(w1.x, P01.x, acc[0][0]);
        acc[0][0] = fmaf(w2.x, P10.x, acc[0][0]); acc[0][0] = fmaf(w3.x, P11.x, acc[0][0]);
        acc[1][0] = fmaf(w0.x, P00.y, acc[1][0]); acc[1][0] = fmaf(w1.x, P01.y, acc[1][0]);
        acc[1][0] = fmaf(w2.x, P10.y, acc[1][0]); acc[1][0] = fmaf(w3.x, P11.y, acc[1][0]);
        acc[2][0] = fmaf(w0.x, P00.z, acc[2][0]); acc[2][0] = fmaf(w1.x, P01.z, acc[2][0]);
        acc[2][0] = fmaf(w2.x, P10.z, acc[2][0]); acc[2][0] = fmaf(w3.x, P11.z, acc[2][0]);
        acc[3][0] = fmaf(w0.x, P00.w, acc[3][0]); acc[3][0] = fmaf(w1.x, P01.w, acc[3][0]);
        acc[3][0] = fmaf(w2.x, P10.w, acc[3][0]); acc[3][0] = fmaf(w3.x, P11.w, acc[3][0]);
        acc[0][1] = fmaf(w0.y, P00.x, acc[0][1]); acc[0][1] = fmaf(w1.y, P01.x, acc[0][1]);
        acc[0][1] = fmaf(w2.y, P10.x, acc[0][1]); acc[0][1] = fmaf(w3.y, P11.x, acc[0][1]);
        acc[1][1] = fmaf(w0.y, P00.y, acc[1][1]); acc[1][1] = fmaf(w1.y, P01.y, acc[1][1]);
        acc[1][1] = fmaf(w2.y, P10.y, acc[1][1]); acc[1][1] = fmaf(w3.y, P11.y, acc[1][1]);
        acc[2][1] = fmaf(w0.y, P00.z, acc[2][1]); acc[2][1] = fmaf(w1.y, P01.z, acc[2][1]);
        acc[2][1] = fmaf(w2.y, P10.z, acc[2][1]); acc[2][1] = fmaf(w3.y, P11.z, acc[2][1]);
        acc[3][1] = fmaf(w0.y, P00.w, acc[3][1]); acc[3][1] = fmaf(w1.y, P01.w, acc[3][1]);
        acc[3][1] = fmaf(w2.y, P10.w, acc[3][1]); acc[3][1] = fmaf(w3.y, P11.w, acc[3][1]);
    }

#pragma unroll
    for (int j = 0; j < 4; ++j) {
        int k = kbase + 2 * j;
#pragma unroll
        for (int c2 = 0; c2 < 2; ++c2) {
            int co = cog * COG + copair * 2 + c2;
            out[((size_t)(k * CO + co)) * 4096 + (Y0 + qy) * R + X0 + qx] = leaky(acc[j][c2]);
        }
    }
}

// ===== dec2k/dec3k: parity 2x2 conv, 1 px x 4 same-parity k per thread ==============
template<int R, int CP, int CO, int CINW, int MINW, bool DOLEAKY>
__global__ void __launch_bounds__(256, MINW) dechalf2_k(
    const float* __restrict__ prev, const float* __restrict__ attn,
    const float* __restrict__ fb, const float* __restrict__ w,
    float* __restrict__ out)
{
    constexpr int Rh = R / 2, TX = R / 16, NCI = CP + 1;
    constexpr int NW = (CO == 4) ? NCI * 16 * 4 : NCI * 16;
    __shared__ float sh4[NCI * 100 * 4];
    __shared__ float wc[NW];

    int t = threadIdx.x;
    int kg = blockIdx.y;
    int p = kg & 1;
    int kbase = (kg >> 1) * 8 + p;
    int tileY = blockIdx.x / TX, tileX = blockIdx.x % TX;
    int Y0 = 16 * tileY, X0 = 16 * tileX;
    int hy0 = 8 * tileY - 1, hx0 = 8 * tileX - 1;

    for (int i = t; i < NW; i += 256) {
        int co, tap, par, ci;
        if (CO == 4) { co = i & 3; tap = (i >> 2) & 3; par = (i >> 4) & 3; ci = i >> 6; }
        else         { co = 0;     tap = i & 3;        par = (i >> 2) & 3; ci = i >> 4; }
        const float* wp = &w[co * CINW * 9 + ci * 9];
        wc[i] = parity_wsum(wp, par >> 1, par & 1, tap >> 1, tap & 1);
    }
#pragma unroll 2
    for (int i = t; i < NCI * 100; i += 256) {
        int c = i / 100, rem = i - c * 100;
        int r = rem / 10, col = rem - r * 10;
        int gy = hy0 + r, gx = hx0 + col;
        bool ok = (gy >= 0) && (gy < Rh) && (gx >= 0) && (gx < Rh);
        int off = gy * Rh + gx;
        float4 v4; v4.x = 0.f; v4.y = 0.f; v4.z = 0.f; v4.w = 0.f;
        if (ok) {
            if (c < CP) {
                v4.x = prev[((size_t)((kbase + 0) * CP + c)) * Rh * Rh + off];
                v4.y = prev[((size_t)((kbase + 2) * CP + c)) * Rh * Rh + off];
                v4.z = prev[((size_t)((kbase + 4) * CP + c)) * Rh * Rh + off];
                v4.w = prev[((size_t)((kbase + 6) * CP + c)) * Rh * Rh + off];
            } else {
                v4.x = attn[(size_t)(kbase + 0) * Rh * Rh + off];
                v4.y = attn[(size_t)(kbase + 2) * Rh * Rh + off];
                v4.z = attn[(size_t)(kbase + 4) * Rh * Rh + off];
                v4.w = attn[(size_t)(kbase + 6) * Rh * Rh + off];
            }
        }
        *(float4*)&sh4[i * 4] = v4;
    }
    __syncthreads();

    int qx = t & 15, qy = t >> 4;
    int par = (qy & 1) * 2 + (qx & 1);
    int rb = (qy + 1) >> 1, cb = (qx + 1) >> 1;
    int o00 = (rb * 10 + cb) * 4;

    float acc[4][CO];
#pragma unroll
    for (int co = 0; co < CO; ++co) {
        float fv = fb[((size_t)(p * CO + co)) * R * R + (Y0 + qy) * R + X0 + qx];
#pragma unroll
        for (int j = 0; j < 4; ++j) acc[j][co] = fv;
    }

#pragma unroll
    for (int ci = 0; ci < NCI; ++ci) {
        const float* hp = &sh4[ci * 400];
        float4 P00 = *(const float4*)&hp[o00];
        float4 P01 = *(const float4*)&hp[o00 + 4];
        float4 P10 = *(const float4*)&hp[o00 + 40];
        float4 P11 = *(const float4*)&hp[o00 + 44];
        const float* Pp[4] = {(const float*)&P00, (const float*)&P01,
                              (const float*)&P10, (const float*)&P11};
        if (CO == 4) {
            const float* wb = &wc[(ci * 4 + par) * 16];
#pragma unroll
            for (int tap = 0; tap < 4; ++tap) {
                float4 wv = *(const float4*)&wb[tap * 4];
                const float* wvp = (const float*)&wv;
                const float* pv = Pp[tap];
#pragma unroll
                for (int co = 0; co < CO; ++co) {
#pragma unroll
                    for (int j = 0; j < 4; ++j)
                        acc[j][co] = fmaf(wvp[co], pv[j], acc[j][co]);
                }
            }
        } else {
            float4 wv = *(const float4*)&wc[(ci * 4 + par) * 4];
            const float* wvp = (const float*)&wv;
#pragma unroll
            for (int tap = 0; tap < 4; ++tap) {
                const float* pv = Pp[tap];
#pragma unroll
                for (int j = 0; j < 4; ++j)
                    acc[j][0] = fmaf(wvp[tap], pv[j], acc[j][0]);
            }
        }
    }

#pragma unroll
    for (int j = 0; j < 4; ++j) {
        int k = kbase + 2 * j;
#pragma unroll
        for (int co = 0; co < CO; ++co) {
            float v = acc[j][co];
            if (DOLEAKY) v = leaky(v);
            out[((size_t)(k * CO + co)) * R * R + (Y0 + qy) * R + X0 + qx] = v;
        }
    }
}

extern "C" void kernel_launch(void* const* d_in, const int* in_sizes, int n_in,
                              void* d_out, int out_size, void* d_ws, size_t ws_size,
                              hipStream_t stream)
{
    (void)in_sizes; (void)n_in; (void)out_size; (void)ws_size;
    const float* x1 = (const float*)d_in[0];
    const float* x2 = (const float*)d_in[1];
    const int* pts = (const int*)d_in[2];
    const float* ew[4] = {(const float*)d_in[3], (const float*)d_in[5],
                          (const float*)d_in[7], (const float*)d_in[9]};
    const float* eb[4] = {(const float*)d_in[4], (const float*)d_in[6],
                          (const float*)d_in[8], (const float*)d_in[10]};
    const float* dw[4] = {(const float*)d_in[11], (const float*)d_in[13],
                          (const float*)d_in[15], (const float*)d_in[17]};
    const float* db[4] = {(const float*)d_in[12], (const float*)d_in[14],
                          (const float*)d_in[16], (const float*)d_in[18]};

    float* wsp = (float*)d_ws;
    size_t off = 0;
    auto A = [&](size_t n) { float* p = wsp + off; off += n; return p; };

    float* p0 = A((size_t)4 * 4 * 128 * 128);
    float* p1 = A((size_t)4 * 8 * 64 * 64);
    float* p2 = A((size_t)4 * 16 * 32 * 32);
    float* p3 = A((size_t)4 * 16 * 16 * 16);
    float* c2_0 = A((size_t)2 * 4 * 256 * 256);
    float* c2_1 = A((size_t)2 * 8 * 128 * 128);
    float* c2_2 = A((size_t)2 * 16 * 64 * 64);
    float* c2_3 = A((size_t)2 * 16 * 32 * 32);
    float* at0 = A((size_t)64 * 128 * 128);
    float* at1 = A((size_t)64 * 64 * 64);
    float* at2 = A((size_t)64 * 32 * 32);
    float* at3 = A((size_t)64 * 16 * 16);
    float* dec0 = A((size_t)64 * 16 * 32 * 32);
    float* dec1 = A((size_t)64 * 8 * 64 * 64);
    float* dec2 = A((size_t)64 * 4 * 128 * 128);
    float* fb0 = A((size_t)2 * 16 * 32 * 32);
    float* fb1 = A((size_t)2 * 8 * 64 * 64);
    float* fb2 = A((size_t)2 * 4 * 128 * 128);
    float* fb3 = A((size_t)2 * 256 * 256);
    float* outp = (float*)d_out;

    // ---- Encoder levels 0-2 ----
    { dim3 g(64, 4); enc0_k<<<g, 256, 0, stream>>>(x1, x2, ew[0], eb[0], c2_0, p0); }
    enc_k<128, 4, 8, 2><<<512, 256, 0, stream>>>(p0, p0 + (size_t)2 * 4 * 128 * 128,
                                                 ew[1], eb[1], c2_1, p1);
    enc_k<64, 8, 16, 2><<<256, 256, 0, stream>>>(p1, p1 + (size_t)2 * 8 * 64 * 64,
                                                 ew[2], eb[2], c2_2, p2);

    // ---- bigprep: enc3 + attn levels 0-2 + fb1/fb2/fb3 ----
    bigprep_k<<<472, 256, 0, stream>>>(p0, p1, p2, pts, ew[3], eb[3], c2_3, p3,
                                       c2_0, c2_1, c2_2,
                                       dw[1], db[1], dw[2], db[2], dw[3], db[3],
                                       at0, at1, at2, fb1, fb2, fb3);

    // ---- prep2: attn3 + fb0 ----
    prep2_k<<<34, 256, 0, stream>>>(p3, c2_3, pts, dw[0], db[0], at3, fb0);

    // ---- Per-k decoder (parity 2x2 convs) ----
    dec0k_k<<<256, 256, 0, stream>>>(at3, fb0, dw[0], dec0);
    { dim3 g(32, 32); dec1k_k<<<g, 256, 0, stream>>>(dec0, at2, fb1, dw[1], dec1); }
    { dim3 g(64, 16); dechalf2_k<128, 8, 4, 17, 4, true><<<g, 256, 0, stream>>>(dec1, at1, fb2, dw[2], dec2); }
    { dim3 g(256, 16); dechalf2_k<256, 4, 1, 9, 5, false><<<g, 256, 0, stream>>>(dec2, at0, fb3, dw[3], outp); }
}

// Round 20
// 125.076 us; speedup vs baseline: 1.1180x; 1.0055x over previous
//
#include <hip/hip_runtime.h>
#include <cstdint>

__device__ __forceinline__ float leaky(float v) { return v >= 0.f ? v : 0.01f * v; }

// ================= Encoder level 0: staged conv5x5 + leaky + pool ====================
__global__ void __launch_bounds__(256) enc0_k(
    const float* __restrict__ x1, const float* __restrict__ x2,
    const float* __restrict__ w, const float* __restrict__ bias,
    float* __restrict__ c2, float* __restrict__ pout)
{
    constexpr int R = 256;
    __shared__ float ss[3 * 36 * 36];
    __shared__ float ws[4 * 3 * 25 + 4];
    int t = threadIdx.x;
    int n = blockIdx.y;
    int tileY = blockIdx.x >> 3, tileX = blockIdx.x & 7;
    int Y0 = 32 * tileY, X0 = 32 * tileX;
    const float* src = (n < 2) ? x1 + (size_t)n * 3 * R * R
                               : x2 + (size_t)(n - 2) * 3 * R * R;

    for (int i = t; i < 300; i += 256) ws[i] = w[i];
    if (t < 4) ws[300 + t] = bias[t];
    for (int ci = 0; ci < 3; ++ci) {
        const float* sp = src + (size_t)ci * R * R;
        for (int i = t; i < 1296; i += 256) {
            int r = i / 36, col = i - r * 36;
            int gy = Y0 - 2 + r, gx = X0 - 2 + col;
            float v = 0.f;
            if (gy >= 0 && gy < R && gx >= 0 && gx < R) v = sp[gy * R + gx];
            ss[ci * 1296 + i] = v;
        }
    }
    __syncthreads();

    int qx = t & 15, qy = t >> 4;
    float acc[4][2][2];
#pragma unroll
    for (int co = 0; co < 4; ++co) {
        float b0 = ws[300 + co];
        acc[co][0][0] = b0; acc[co][0][1] = b0; acc[co][1][0] = b0; acc[co][1][1] = b0;
    }
#pragma unroll
    for (int ci = 0; ci < 3; ++ci) {
        const float* sp = &ss[ci * 1296 + (2 * qy) * 36 + 2 * qx];
        float S[6][6];
#pragma unroll
        for (int i = 0; i < 6; ++i)
#pragma unroll
            for (int j = 0; j < 6; ++j) S[i][j] = sp[i * 36 + j];
#pragma unroll
        for (int co = 0; co < 4; ++co) {
#pragma unroll
            for (int dy = 0; dy < 5; ++dy) {
#pragma unroll
                for (int dx = 0; dx < 5; ++dx) {
                    float wv = ws[(co * 3 + ci) * 25 + dy * 5 + dx];
                    acc[co][0][0] = fmaf(wv, S[dy][dx],         acc[co][0][0]);
                    acc[co][0][1] = fmaf(wv, S[dy][dx + 1],     acc[co][0][1]);
                    acc[co][1][0] = fmaf(wv, S[dy + 1][dx],     acc[co][1][0]);
                    acc[co][1][1] = fmaf(wv, S[dy + 1][dx + 1], acc[co][1][1]);
                }
            }
        }
    }
#pragma unroll
    for (int co = 0; co < 4; ++co) {
        float v00 = leaky(acc[co][0][0]), v01 = leaky(acc[co][0][1]);
        float v10 = leaky(acc[co][1][0]), v11 = leaky(acc[co][1][1]);
        if (n >= 2) {
            float* op = c2 + ((size_t)((n - 2) * 4 + co)) * R * R + (Y0 + 2 * qy) * R + X0 + 2 * qx;
            float2 a; a.x = v00; a.y = v01; *(float2*)op = a;
            float2 b2; b2.x = v10; b2.y = v11; *(float2*)(op + R) = b2;
        }
        float pv = fmaxf(fmaxf(v00, v01), fmaxf(v10, v11));
        pout[((size_t)(n * 4 + co)) * 16384 + (16 * tileY + qy) * 128 + 16 * tileX + qx] = pv;
    }
}

// ================= Encoder body: conv5x5 pad2 + leaky + fused 2x2 maxpool ============
template<int R, int CI, int CO, int COG>
__device__ __forceinline__ void enc_body(
    const float* __restrict__ src1, const float* __restrict__ src2,
    const float* __restrict__ w, const float* __restrict__ bias,
    float* __restrict__ c2, float* __restrict__ pout, int bx)
{
    constexpr int W = R, H = R, Wt = R / 2;
    constexpr int RPB = 256 / Wt;
    __shared__ float ws[COG * CI * 25];
    __shared__ float pl[(RPB / 2) * COG * Wt];

    int t = threadIdx.x;
    int gid = bx * 256 + t;
    int col = gid % Wt;
    int y = (gid / Wt) % H;
    int n = (gid / (Wt * H)) & 3;
    int g = gid / (Wt * H * 4);

    if (COG == 2) {
        for (int i = t; i < COG * CI * 25; i += 256) {
            int cg = i & 1, idx = i >> 1;
            ws[idx * 2 + cg] = w[(g * COG + cg) * CI * 25 + idx];
        }
    } else {
        for (int i = t; i < COG * CI * 25; i += 256) ws[i] = w[g * COG * CI * 25 + i];
    }
    __syncthreads();

    const float* sp = (n < 2) ? (src1 + (size_t)n * CI * H * W)
                              : (src2 + (size_t)(n - 2) * CI * H * W);
    int x0 = col * 2;

    float acc[COG][2];
#pragma unroll
    for (int cg = 0; cg < COG; ++cg) { float b0 = bias[g * COG + cg]; acc[cg][0] = b0; acc[cg][1] = b0; }

    bool okr[5], okc[3];
#pragma unroll
    for (int i = 0; i < 5; ++i) { int yy = y + i - 2; okr[i] = (yy >= 0) && (yy < H); }
#pragma unroll
    for (int j = 0; j < 3; ++j) { int xx = x0 + 2 * j - 2; okc[j] = (xx >= 0) && (xx < W); }

#pragma unroll 4
    for (int ci = 0; ci < CI; ++ci) {
        const float* s = sp + ci * H * W + (y - 2) * W + (x0 - 2);
        float p[5][6];
#pragma unroll
        for (int i = 0; i < 5; ++i) {
#pragma unroll
            for (int j = 0; j < 3; ++j) {
                if (okr[i] & okc[j]) {
                    float2 v = *(const float2*)(s + i * W + 2 * j);
                    p[i][2 * j] = v.x; p[i][2 * j + 1] = v.y;
                } else { p[i][2 * j] = 0.f; p[i][2 * j + 1] = 0.f; }
            }
        }
        if (COG == 2) {
#pragma unroll
            for (int dy = 0; dy < 5; ++dy) {
#pragma unroll
                for (int dx = 0; dx < 5; ++dx) {
                    float2 wv = *(const float2*)&ws[(ci * 25 + dy * 5 + dx) * 2];
                    acc[0][0] = fmaf(wv.x, p[dy][dx],     acc[0][0]);
                    acc[0][1] = fmaf(wv.x, p[dy][dx + 1], acc[0][1]);
                    acc[1][0] = fmaf(wv.y, p[dy][dx],     acc[1][0]);
                    acc[1][1] = fmaf(wv.y, p[dy][dx + 1], acc[1][1]);
                }
            }
        } else {
#pragma unroll
            for (int cg = 0; cg < COG; ++cg) {
#pragma unroll
                for (int dy = 0; dy < 5; ++dy) {
#pragma unroll
                    for (int dx = 0; dx < 5; ++dx) {
                        float wv = ws[(cg * CI + ci) * 25 + dy * 5 + dx];
                        acc[cg][0] = fmaf(wv, p[dy][dx],     acc[cg][0]);
                        acc[cg][1] = fmaf(wv, p[dy][dx + 1], acc[cg][1]);
                    }
                }
            }
        }
    }

    int r = t / Wt;
    float m[COG];
#pragma unroll
    for (int cg = 0; cg < COG; ++cg) {
        float v0 = leaky(acc[cg][0]), v1 = leaky(acc[cg][1]);
        m[cg] = fmaxf(v0, v1);
        if (n >= 2) {
            float2 stv; stv.x = v0; stv.y = v1;
            *(float2*)(c2 + ((size_t)((n - 2) * CO + g * COG + cg)) * H * W + y * W + x0) = stv;
        }
    }
    if (r & 1) {
#pragma unroll
        for (int cg = 0; cg < COG; ++cg)
            pl[((r >> 1) * COG + cg) * Wt + col] = m[cg];
    }
    __syncthreads();
    if (!(r & 1)) {
#pragma unroll
        for (int cg = 0; cg < COG; ++cg) {
            float pv = fmaxf(m[cg], pl[((r >> 1) * COG + cg) * Wt + col]);
            pout[((size_t)(n * CO + g * COG + cg)) * Wt * Wt + (y >> 1) * Wt + col] = pv;
        }
    }
}

template<int R, int CI, int CO, int COG>
__global__ void __launch_bounds__(256) enc_k(
    const float* __restrict__ src1, const float* __restrict__ src2,
    const float* __restrict__ w, const float* __restrict__ bias,
    float* __restrict__ c2, float* __restrict__ pout)
{
    enc_body<R, CI, CO, COG>(src1, src2, w, bias, c2, pout, blockIdx.x);
}

// ================= Attention body ====================================================
template<int C, int RP, int SHIFT>
__device__ __forceinline__ void attn_body(
    const float* __restrict__ pool, const int* __restrict__ pts,
    float* __restrict__ out, int tile, int b)
{
    constexpr int P = RP * RP;
    __shared__ float qs[32 * C];
    int t = threadIdx.x;
    if (t < 32) {
        int l = t;
        int py = pts[(b * 32 + l) * 2 + 0] >> SHIFT;
        int px = pts[(b * 32 + l) * 2 + 1] >> SHIFT;
        const float* qp = pool + (size_t)(b * C) * P + py * RP + px;
        float v[C]; float s = 0.f;
#pragma unroll
        for (int c = 0; c < C; ++c) { v[c] = qp[c * P]; s += v[c] * v[c]; }
        float invn = 1.f / fmaxf(sqrtf(s), 1e-8f);
#pragma unroll
        for (int c = 0; c < C; ++c) qs[l * C + c] = v[c] * invn;
    }
    __syncthreads();
    int p = tile * 256 + t;
    const float* hp = pool + (size_t)((2 + b) * C) * P + p;
    float v[C]; float s = 0.f;
#pragma unroll
    for (int c = 0; c < C; ++c) { v[c] = hp[c * P]; s += v[c] * v[c]; }
    float invn2 = 1.f / fmaxf(sqrtf(s), 1e-8f);
#pragma unroll 4
    for (int l = 0; l < 32; ++l) {
        float d = 0.f;
#pragma unroll
        for (int c = 0; c < C; ++c) d = fmaf(v[c], qs[l * C + c], d);
        out[(size_t)(b * 32 + l) * P + p] = d * invn2;
    }
}

// ========= parity-group helper: combined 2x2 weights from 3x3 upsample conv =========
__device__ __forceinline__ float parity_wsum(const float* wp, int py, int pxr, int ti, int tj)
{
    int dy0 = (py == 0) ? (ti == 0 ? 0 : 1) : (ti == 0 ? 0 : 2);
    int dy1 = (py == 0) ? (ti == 0 ? 0 : 2) : (ti == 0 ? 1 : 2);
    int dx0 = (pxr == 0) ? (tj == 0 ? 0 : 1) : (tj == 0 ? 0 : 2);
    int dx1 = (pxr == 0) ? (tj == 0 ? 0 : 2) : (tj == 0 ? 1 : 2);
    float s = 0.f;
    for (int dy = dy0; dy <= dy1; ++dy)
        for (int dx = dx0; dx <= dx1; ++dx) s += wp[dy * 3 + dx];
    return s;
}

// ================= Parity feature-base bodies ========================================
template<int R, int CI, int CINW, int CO, int COG>
__device__ __forceinline__ void fb_body(
    const float* __restrict__ in, const float* __restrict__ w,
    const float* __restrict__ bias, float* __restrict__ fb,
    int par, int tile, int cog)
{
    constexpr int QD = R / 2;
    __shared__ float ws[COG * CI * 9];
    int t = threadIdx.x;
    for (int i = t; i < COG * CI * 9; i += 256) {
        int co = i / (CI * 9), rem = i - co * (CI * 9);
        ws[i] = w[(cog * COG + co) * CINW * 9 + (CINW - CI) * 9 + rem];
    }
    __syncthreads();
    int q = tile * 256 + t;
    int qx = q % QD, qy = q / QD;
    const float* ip = in + (size_t)par * CI * R * R;
    float acc[COG][2][2];
#pragma unroll
    for (int co = 0; co < COG; ++co) {
        float b0 = bias[cog * COG + co];
        acc[co][0][0] = b0; acc[co][0][1] = b0; acc[co][1][0] = b0; acc[co][1][1] = b0;
    }
    bool fr[4], fc[4];
#pragma unroll
    for (int i = 0; i < 4; ++i) {
        int yy = 2 * qy - 1 + i; fr[i] = (yy >= 0) && (yy < R);
        int xx = 2 * qx - 1 + i; fc[i] = (xx >= 0) && (xx < R);
    }
#pragma unroll 4
    for (int ci = 0; ci < CI; ++ci) {
        const float* bp = ip + (size_t)ci * R * R + (2 * qy - 1) * R + (2 * qx - 1);
        float F[4][4];
#pragma unroll
        for (int i = 0; i < 4; ++i)
#pragma unroll
            for (int j = 0; j < 4; ++j)
                F[i][j] = (fr[i] & fc[j]) ? bp[i * R + j] : 0.f;
#pragma unroll
        for (int co = 0; co < COG; ++co) {
#pragma unroll
            for (int dy = 0; dy < 3; ++dy) {
#pragma unroll
                for (int dx = 0; dx < 3; ++dx) {
                    float wv = ws[(co * CI + ci) * 9 + dy * 3 + dx];
                    acc[co][0][0] = fmaf(wv, F[dy][dx],         acc[co][0][0]);
                    acc[co][0][1] = fmaf(wv, F[dy][dx + 1],     acc[co][0][1]);
                    acc[co][1][0] = fmaf(wv, F[dy + 1][dx],     acc[co][1][0]);
                    acc[co][1][1] = fmaf(wv, F[dy + 1][dx + 1], acc[co][1][1]);
                }
            }
        }
    }
#pragma unroll
    for (int co = 0; co < COG; ++co) {
        float* op = fb + ((size_t)(par * CO + cog * COG + co)) * R * R + (2 * qy) * R + 2 * qx;
        float2 a; a.x = acc[co][0][0]; a.y = acc[co][0][1]; *(float2*)op = a;
        float2 b2; b2.x = acc[co][1][0]; b2.y = acc[co][1][1]; *(float2*)(op + R) = b2;
    }
}

// fb0: prev (upsampled p3) via parity 2x2; feat (full-res c2_3) via 3x3.
__device__ __forceinline__ void fb0_body(
    const float* __restrict__ p3, const float* __restrict__ c2_3,
    const float* __restrict__ w, const float* __restrict__ bias,
    float* __restrict__ fb0, int par_img, int tile, int cog)
{
    __shared__ float wcp[16 * 4 * 4 * 4];   // ((ci*4+par)*4+tap)*4+co
    __shared__ float wf[4 * 16 * 9];        // (co*16+cf)*9+tap
    int t = threadIdx.x;
    for (int i = t; i < 1024; i += 256) {
        int co = i & 3, tap = (i >> 2) & 3, par = (i >> 4) & 3, ci = i >> 6;
        const float* wp = &w[(cog * 4 + co) * 33 * 9 + ci * 9];
        wcp[i] = parity_wsum(wp, par >> 1, par & 1, tap >> 1, tap & 1);
    }
    for (int i = t; i < 576; i += 256) {
        int tap = i % 9, rem = i / 9;
        int cf = rem & 15, co = rem >> 4;
        wf[i] = w[(cog * 4 + co) * 33 * 9 + (17 + cf) * 9 + tap];
    }
    __syncthreads();
    int px = tile * 256 + t;
    int x = px & 31, y = px >> 5;
    const float* prevp = p3 + (size_t)(2 + par_img) * 16 * 256;
    const float* featp = c2_3 + (size_t)par_img * 16 * 1024;
    float acc[4];
#pragma unroll
    for (int co = 0; co < 4; ++co) acc[co] = bias[cog * 4 + co];

    // --- prev: parity 2x2 on half grid 16x16 ---
    int par = (y & 1) * 2 + (x & 1);
    int rb = ((y + 1) >> 1) - 1, cb = ((x + 1) >> 1) - 1;
    bool ry[2] = {rb >= 0 && rb < 16, rb + 1 >= 0 && rb + 1 < 16};
    bool cxo[2] = {cb >= 0 && cb < 16, cb + 1 >= 0 && cb + 1 < 16};
#pragma unroll 4
    for (int ci = 0; ci < 16; ++ci) {
        const float* pp = prevp + ci * 256;
        float V2[2][2];
#pragma unroll
        for (int i = 0; i < 2; ++i)
#pragma unroll
            for (int j = 0; j < 2; ++j)
                V2[i][j] = (ry[i] && cxo[j]) ? pp[(rb + i) * 16 + (cb + j)] : 0.f;
        const float* wb = &wcp[(ci * 4 + par) * 16];
#pragma unroll
        for (int tap = 0; tap < 4; ++tap) {
            float av = V2[tap >> 1][tap & 1];
            float4 wv = *(const float4*)&wb[tap * 4];
            acc[0] = fmaf(wv.x, av, acc[0]);
            acc[1] = fmaf(wv.y, av, acc[1]);
            acc[2] = fmaf(wv.z, av, acc[2]);
            acc[3] = fmaf(wv.w, av, acc[3]);
        }
    }

    // --- feat: full-res 3x3 ---
    bool oky[3], okx[3];
#pragma unroll
    for (int i = 0; i < 3; ++i) {
        int iy = y - 1 + i; oky[i] = (iy >= 0) && (iy < 32);
        int ix = x - 1 + i; okx[i] = (ix >= 0) && (ix < 32);
    }
#pragma unroll 4
    for (int cf = 0; cf < 16; ++cf) {
        const float* fp = featp + cf * 1024;
        float F[3][3];
#pragma unroll
        for (int i = 0; i < 3; ++i)
#pragma unroll
            for (int j = 0; j < 3; ++j) {
                int iy = y - 1 + i, ix = x - 1 + j;
                F[i][j] = (oky[i] & okx[j]) ? fp[iy * 32 + ix] : 0.f;
            }
#pragma unroll
        for (int co = 0; co < 4; ++co) {
#pragma unroll
            for (int tap = 0; tap < 9; ++tap)
                acc[co] = fmaf(wf[(co * 16 + cf) * 9 + tap], F[tap / 3][tap % 3], acc[co]);
        }
    }
#pragma unroll
    for (int co = 0; co < 4; ++co)
        fb0[((size_t)(par_img * 16 + cog * 4 + co)) * 1024 + y * 32 + x] = acc[co];
}

// ========== bigprep: enc3 + attn levels 0-2 + fb1/fb2/fb3 in one launch =============
__global__ void __launch_bounds__(256) bigprep_k(
    const float* __restrict__ p0, const float* __restrict__ p1,
    const float* __restrict__ p2, const int* __restrict__ pts,
    const float* __restrict__ ew3, const float* __restrict__ eb3,
    float* __restrict__ c2_3, float* __restrict__ p3,
    const float* __restrict__ c2_0, const float* __restrict__ c2_1,
    const float* __restrict__ c2_2,
    const float* __restrict__ dw1, const float* __restrict__ db1,
    const float* __restrict__ dw2, const float* __restrict__ db2,
    const float* __restrict__ dw3, const float* __restrict__ db3,
    float* __restrict__ at0, float* __restrict__ at1, float* __restrict__ at2,
    float* __restrict__ fb1, float* __restrict__ fb2, float* __restrict__ fb3)
{
    int bx = blockIdx.x;
    if (bx < 128) {
        enc_body<32, 16, 16, 1>(p2, p2 + (size_t)2 * 16 * 32 * 32, ew3, eb3, c2_3, p3, bx);
    } else if (bx < 256) {
        int r = bx - 128; attn_body<4, 128, 1>(p0, pts, at0, r >> 1, r & 1);
    } else if (bx < 288) {
        int r = bx - 256; attn_body<8, 64, 2>(p1, pts, at1, r >> 1, r & 1);
    } else if (bx < 296) {
        int r = bx - 288; attn_body<16, 32, 3>(p2, pts, at2, r >> 1, r & 1);
    } else if (bx < 424) {
        int sub = bx - 296; int par = sub >> 6, tile = sub & 63;
        fb_body<256, 4, 9, 1, 1>(c2_0, dw3, db3, fb3, par, tile, 0);
    } else if (bx < 456) {
        int sub = bx - 424; int par = sub >> 4, tile = sub & 15;
        fb_body<128, 8, 17, 4, 4>(c2_1, dw2, db2, fb2, par, tile, 0);
    } else {
        int sub = bx - 456; int cog = sub & 1, tile = (sub >> 1) & 3, par = sub >> 3;
        fb_body<64, 16, 33, 8, 4>(c2_2, dw1, db1, fb1, par, tile, cog);
    }
}

// ========== prep2: attn level 3 + fb0 (need enc3 outputs) ===========================
__global__ void __launch_bounds__(256) prep2_k(
    const float* __restrict__ p3, const float* __restrict__ c2_3,
    const int* __restrict__ pts,
    const float* __restrict__ dw0, const float* __restrict__ db0,
    float* __restrict__ at3, float* __restrict__ fb0)
{
    int bx = blockIdx.x;
    if (bx < 2) {
        attn_body<16, 16, 4>(p3, pts, at3, bx >> 1, bx & 1);
    } else {
        int sub = bx - 2; int cog = sub & 3, tile = (sub >> 2) & 3, par = sub >> 4;
        fb0_body(p3, c2_3, dw0, db0, fb0, par, tile, cog);
    }
}

// ============ dec0k: out = leaky(fb0[k&1] + parity2x2(at3[k])) ======================
__global__ void __launch_bounds__(256) dec0k_k(
    const float* __restrict__ at3, const float* __restrict__ fb0,
    const float* __restrict__ w, float* __restrict__ out)
{
    __shared__ float wc2[4 * 4 * 16];   // ((par*4+tap)*16+co)
    int t = threadIdx.x;
    {
        int co = t & 15, tap = (t >> 4) & 3, par = t >> 6;
        const float* wp = &w[co * 33 * 9 + 16 * 9];
        wc2[(par * 4 + tap) * 16 + co] = parity_wsum(wp, par >> 1, par & 1, tap >> 1, tap & 1);
    }
    __syncthreads();
    int gid = blockIdx.x;
    int k = gid >> 2, tile = gid & 3;
    int px = tile * 256 + t;
    int x = px & 31, y = px >> 5;
    int kpar = k & 1;
    const float* ap = at3 + (size_t)k * 256;

    int rb = ((y + 1) >> 1) - 1, cb = ((x + 1) >> 1) - 1;
    float A2[2][2];
#pragma unroll
    for (int i = 0; i < 2; ++i) {
        int r = rb + i; bool oy = (r >= 0) && (r < 16);
#pragma unroll
        for (int j = 0; j < 2; ++j) {
            int c = cb + j; bool ox = (c >= 0) && (c < 16);
            A2[i][j] = (oy && ox) ? ap[r * 16 + c] : 0.f;
        }
    }
    int par = (y & 1) * 2 + (x & 1);
    float acc[16];
#pragma unroll
    for (int co = 0; co < 16; ++co)
        acc[co] = fb0[((size_t)(kpar * 16 + co)) * 1024 + y * 32 + x];
#pragma unroll
    for (int tap = 0; tap < 4; ++tap) {
        float av = A2[tap >> 1][tap & 1];
        const float* wb = &wc2[(par * 4 + tap) * 16];
#pragma unroll
        for (int c4 = 0; c4 < 4; ++c4) {
            float4 wv = *(const float4*)&wb[c4 * 4];
            acc[c4 * 4 + 0] = fmaf(wv.x, av, acc[c4 * 4 + 0]);
            acc[c4 * 4 + 1] = fmaf(wv.y, av, acc[c4 * 4 + 1]);
            acc[c4 * 4 + 2] = fmaf(wv.z, av, acc[c4 * 4 + 2]);
            acc[c4 * 4 + 3] = fmaf(wv.w, av, acc[c4 * 4 + 3]);
        }
    }
#pragma unroll
    for (int co = 0; co < 16; ++co)
        out[((size_t)(k * 16 + co)) * 1024 + y * 32 + x] = leaky(acc[co]);
}

// ============ dec1k: parity 2x2 conv, 16x8 tile, 4 same-parity k x 2 co =============
__global__ void __launch_bounds__(256, 4) dec1k_k(
    const float* __restrict__ prev, const float* __restrict__ attn,
    const float* __restrict__ fb1, const float* __restrict__ w,
    float* __restrict__ out)
{
    constexpr int R = 64, CP = 16, CIN = 33, Rh = 32, CO = 8, COG = 4, NCI = 17;
    __shared__ float wc[NCI * 16 * COG];          // ((ci*4+par)*4+tap)*4+co
    __shared__ float sh4[NCI * 60 * 4];

    int t = threadIdx.x;
    int bz = blockIdx.y;
    int kg = bz >> 1, cog = bz & 1;
    int p = kg & 1;
    int kbase = (kg >> 1) * 8 + p;
    int tileY = blockIdx.x >> 2, tileX = blockIdx.x & 3;
    int Y0 = 8 * tileY, X0 = 16 * tileX;
    int hy0 = 4 * tileY - 1, hx0 = 8 * tileX - 1;

    for (int i = t; i < NCI * 16 * COG; i += 256) {
        int co = i & 3, tap = (i >> 2) & 3, par = (i >> 4) & 3, ci = i >> 6;
        const float* wp = &w[(cog * COG + co) * CIN * 9 + ci * 9];
        wc[i] = parity_wsum(wp, par >> 1, par & 1, tap >> 1, tap & 1);
    }
#pragma unroll 2
    for (int i = t; i < NCI * 60; i += 256) {
        int c = i / 60, rem = i - c * 60;
        int r = rem / 10, col = rem - r * 10;
        int gy = hy0 + r, gx = hx0 + col;
        bool ok = (gy >= 0) && (gy < Rh) && (gx >= 0) && (gx < Rh);
        int off = gy * Rh + gx;
        float4 v4; v4.x = 0.f; v4.y = 0.f; v4.z = 0.f; v4.w = 0.f;
        if (ok) {
            if (c < CP) {
                v4.x = prev[((size_t)((kbase + 0) * CP + c)) * Rh * Rh + off];
                v4.y = prev[((size_t)((kbase + 2) * CP + c)) * Rh * Rh + off];
                v4.z = prev[((size_t)((kbase + 4) * CP + c)) * Rh * Rh + off];
                v4.w = prev[((size_t)((kbase + 6) * CP + c)) * Rh * Rh + off];
            } else {
                v4.x = attn[(size_t)(kbase + 0) * Rh * Rh + off];
                v4.y = attn[(size_t)(kbase + 2) * Rh * Rh + off];
                v4.z = attn[(size_t)(kbase + 4) * Rh * Rh + off];
                v4.w = attn[(size_t)(kbase + 6) * Rh * Rh + off];
            }
        }
        *(float4*)&sh4[i * 4] = v4;
    }
    __syncthreads();

    int px = t & 127, copair = t >> 7;
    int qx = px & 15, qy = px >> 4;
    int par = (qy & 1) * 2 + (qx & 1);
    int rb = (qy + 1) >> 1, cb = (qx + 1) >> 1;
    int o00 = (rb * 10 + cb) * 4;

    float acc[4][2];
#pragma unroll
    for (int c2 = 0; c2 < 2; ++c2) {
        float fv = fb1[((size_t)(p * CO + cog * COG + copair * 2 + c2)) * 4096 + (Y0 + qy) * R + X0 + qx];
#pragma unroll
        for (int j = 0; j < 4; ++j) acc[j][c2] = fv;
    }

#pragma unroll 4
    for (int ci = 0; ci < NCI; ++ci) {
        const float* hp = &sh4[ci * 240];
        float4 P00 = *(const float4*)&hp[o00];
        float4 P01 = *(const float4*)&hp[o00 + 4];
        float4 P10 = *(const float4*)&hp[o00 + 40];
        float4 P11 = *(const float4*)&hp[o00 + 44];
        const float* wb = &wc[(ci * 4 + par) * 16 + copair * 2];
        float2 w0 = *(const float2*)&wb[0];
        float2 w1 = *(const float2*)&wb[4];
        float2 w2 = *(const float2*)&wb[8];
        float2 w3 = *(const float2*)&wb[12];
        acc[0][0] = fmaf(w0.x, P00.x, acc[0][0]); acc[0][0] = fmaf(w1.x, P01.x, acc[0][0]);
        acc[0][0] = fmaf(w2.x, P10.x, acc[0][0]); acc[0][0] = fmaf(w3.x, P11.x, acc[0][0]);
        acc[1][0] = fmaf(w0.x, P00.y, acc[1][0]); acc[1][0] = fmaf(w1.x, P01.y, acc[1][0]);
        acc[1][0] = fmaf(w2.x, P10.y, acc[1][0]); acc[1][0] = fmaf(w3.x, P11.y, acc[1][0]);
        acc[2][0] = fmaf(w0.x, P00.z, acc[2][0]); acc[2][0] = fmaf(w1.x, P01.z, acc[2][0]);
        acc[2][0] = fmaf(w2.x, P10.z, acc[2][0]); acc[2][0] = fmaf(w3.x, P11.z, acc[2][0]);
        acc[3][0] = fmaf(w0.x, P00.w, acc[3][0]); acc[3][0] = fmaf(w1.x, P01.w, acc[3][0]);
        acc[3][0] = fmaf(w2.x, P10.w, acc[3][0]); acc[3][0] = fmaf(w3.x, P11.w, acc[3][0]);
        acc[0][1] = fmaf(w0.y, P00.x, acc[0][1]); acc[0][1] = fmaf(w1.y, P01.x, acc[0][1]);
        acc[0][1] = fmaf(w2.y, P10.x, acc[0][1]); acc[0][1] = fmaf(w3.y, P11.x, acc[0][1]);
        acc[1][1] = fmaf(w0.y, P00.y, acc[1][1]); acc[1][1] = fmaf(w1.y, P01.y, acc[1][1]);
        acc[1][1] = fmaf(w2.y, P10.y, acc[1][1]); acc[1][1] = fmaf(w3.y, P11.y, acc[1][1]);
        acc[2][1] = fmaf(w0.y, P00.z, acc[2][1]); acc[2][1] = fmaf(w1.y, P01.z, acc[2][1]);
        acc[2][1] = fmaf(w2.y, P10.z, acc[2][1]); acc[2][1] = fmaf(w3.y, P11.z, acc[2][1]);
        acc[3][1] = fmaf(w0.y, P00.w, acc[3][1]); acc[3][1] = fmaf(w1.y, P01.w, acc[3][1]);
        acc[3][1] = fmaf(w2.y, P10.w, acc[3][1]); acc[3][1] = fmaf(w3.y, P11.w, acc[3][1]);
    }

#pragma unroll
    for (int j = 0; j < 4; ++j) {
        int k = kbase + 2 * j;
#pragma unroll
        for (int c2 = 0; c2 < 2; ++c2) {
            int co = cog * COG + copair * 2 + c2;
            out[((size_t)(k * CO + co)) * 4096 + (Y0 + qy) * R + X0 + qx] = leaky(acc[j][c2]);
        }
    }
}

// ===== dec2k/dec3k: parity 2x2 conv, 1 px x 4 same-parity k per thread ==============
template<int R, int CP, int CO, int CINW, int MINW, bool DOLEAKY>
__global__ void __launch_bounds__(256, MINW) dechalf2_k(
    const float* __restrict__ prev, const float* __restrict__ attn,
    const float* __restrict__ fb, const float* __restrict__ w,
    float* __restrict__ out)
{
    constexpr int Rh = R / 2, TX = R / 16, NCI = CP + 1;
    constexpr int NW = (CO == 4) ? NCI * 16 * 4 : NCI * 16;
    __shared__ float sh4[NCI * 100 * 4];
    __shared__ float wc[NW];

    int t = threadIdx.x;
    int kg = blockIdx.y;
    int p = kg & 1;
    int kbase = (kg >> 1) * 8 + p;
    int tileY = blockIdx.x / TX, tileX = blockIdx.x % TX;
    int Y0 = 16 * tileY, X0 = 16 * tileX;
    int hy0 = 8 * tileY - 1, hx0 = 8 * tileX - 1;

    for (int i = t; i < NW; i += 256) {
        int co, tap, par, ci;
        if (CO == 4) { co = i & 3; tap = (i >> 2) & 3; par = (i >> 4) & 3; ci = i >> 6; }
        else         { co = 0;     tap = i & 3;        par = (i >> 2) & 3; ci = i >> 4; }
        const float* wp = &w[co * CINW * 9 + ci * 9];
        wc[i] = parity_wsum(wp, par >> 1, par & 1, tap >> 1, tap & 1);
    }
#pragma unroll 2
    for (int i = t; i < NCI * 100; i += 256) {
        int c = i / 100, rem = i - c * 100;
        int r = rem / 10, col = rem - r * 10;
        int gy = hy0 + r, gx = hx0 + col;
        bool ok = (gy >= 0) && (gy < Rh) && (gx >= 0) && (gx < Rh);
        int off = gy * Rh + gx;
        float4 v4; v4.x = 0.f; v4.y = 0.f; v4.z = 0.f; v4.w = 0.f;
        if (ok) {
            if (c < CP) {
                v4.x = prev[((size_t)((kbase + 0) * CP + c)) * Rh * Rh + off];
                v4.y = prev[((size_t)((kbase + 2) * CP + c)) * Rh * Rh + off];
                v4.z = prev[((size_t)((kbase + 4) * CP + c)) * Rh * Rh + off];
                v4.w = prev[((size_t)((kbase + 6) * CP + c)) * Rh * Rh + off];
            } else {
                v4.x = attn[(size_t)(kbase + 0) * Rh * Rh + off];
                v4.y = attn[(size_t)(kbase + 2) * Rh * Rh + off];
                v4.z = attn[(size_t)(kbase + 4) * Rh * Rh + off];
                v4.w = attn[(size_t)(kbase + 6) * Rh * Rh + off];
            }
        }
        *(float4*)&sh4[i * 4] = v4;
    }
    __syncthreads();

    int qx = t & 15, qy = t >> 4;
    int par = (qy & 1) * 2 + (qx & 1);
    int rb = (qy + 1) >> 1, cb = (qx + 1) >> 1;
    int o00 = (rb * 10 + cb) * 4;

    float acc[4][CO];
#pragma unroll
    for (int co = 0; co < CO; ++co) {
        float fv = fb[((size_t)(p * CO + co)) * R * R + (Y0 + qy) * R + X0 + qx];
#pragma unroll
        for (int j = 0; j < 4; ++j) acc[j][co] = fv;
    }

#pragma unroll
    for (int ci = 0; ci < NCI; ++ci) {
        const float* hp = &sh4[ci * 400];
        float4 P00 = *(const float4*)&hp[o00];
        float4 P01 = *(const float4*)&hp[o00 + 4];
        float4 P10 = *(const float4*)&hp[o00 + 40];
        float4 P11 = *(const float4*)&hp[o00 + 44];
        const float* Pp[4] = {(const float*)&P00, (const float*)&P01,
                              (const float*)&P10, (const float*)&P11};
        if (CO == 4) {
            const float* wb = &wc[(ci * 4 + par) * 16];
#pragma unroll
            for (int tap = 0; tap < 4; ++tap) {
                float4 wv = *(const float4*)&wb[tap * 4];
                const float* wvp = (const float*)&wv;
                const float* pv = Pp[tap];
#pragma unroll
                for (int co = 0; co < CO; ++co) {
#pragma unroll
                    for (int j = 0; j < 4; ++j)
                        acc[j][co] = fmaf(wvp[co], pv[j], acc[j][co]);
                }
            }
        } else {
            float4 wv = *(const float4*)&wc[(ci * 4 + par) * 4];
            const float* wvp = (const float*)&wv;
#pragma unroll
            for (int tap = 0; tap < 4; ++tap) {
                const float* pv = Pp[tap];
#pragma unroll
                for (int j = 0; j < 4; ++j)
                    acc[j][0] = fmaf(wvp[tap], pv[j], acc[j][0]);
            }
        }
    }

#pragma unroll
    for (int j = 0; j < 4; ++j) {
        int k = kbase + 2 * j;
#pragma unroll
        for (int co = 0; co < CO; ++co) {
            float v = acc[j][co];
            if (DOLEAKY) v = leaky(v);
            out[((size_t)(k * CO + co)) * R * R + (Y0 + qy) * R + X0 + qx] = v;
        }
    }
}

extern "C" void kernel_launch(void* const* d_in, const int* in_sizes, int n_in,
                              void* d_out, int out_size, void* d_ws, size_t ws_size,
                              hipStream_t stream)
{
    (void)in_sizes; (void)n_in; (void)out_size; (void)ws_size;
    const float* x1 = (const float*)d_in[0];
    const float* x2 = (const float*)d_in[1];
    const int* pts = (const int*)d_in[2];
    const float* ew[4] = {(const float*)d_in[3], (const float*)d_in[5],
                          (const float*)d_in[7], (const float*)d_in[9]};
    const float* eb[4] = {(const float*)d_in[4], (const float*)d_in[6],
                          (const float*)d_in[8], (const float*)d_in[10]};
    const float* dw[4] = {(const float*)d_in[11], (const float*)d_in[13],
                          (const float*)d_in[15], (const float*)d_in[17]};
    const float* db[4] = {(const float*)d_in[12], (const float*)d_in[14],
                          (const float*)d_in[16], (const float*)d_in[18]};

    float* wsp = (float*)d_ws;
    size_t off = 0;
    auto A = [&](size_t n) { float* p = wsp + off; off += n; return p; };

    float* p0 = A((size_t)4 * 4 * 128 * 128);
    float* p1 = A((size_t)4 * 8 * 64 * 64);
    float* p2 = A((size_t)4 * 16 * 32 * 32);
    float* p3 = A((size_t)4 * 16 * 16 * 16);
    float* c2_0 = A((size_t)2 * 4 * 256 * 256);
    float* c2_1 = A((size_t)2 * 8 * 128 * 128);
    float* c2_2 = A((size_t)2 * 16 * 64 * 64);
    float* c2_3 = A((size_t)2 * 16 * 32 * 32);
    float* at0 = A((size_t)64 * 128 * 128);
    float* at1 = A((size_t)64 * 64 * 64);
    float* at2 = A((size_t)64 * 32 * 32);
    float* at3 = A((size_t)64 * 16 * 16);
    float* dec0 = A((size_t)64 * 16 * 32 * 32);
    float* dec1 = A((size_t)64 * 8 * 64 * 64);
    float* dec2 = A((size_t)64 * 4 * 128 * 128);
    float* fb0 = A((size_t)2 * 16 * 32 * 32);
    float* fb1 = A((size_t)2 * 8 * 64 * 64);
    float* fb2 = A((size_t)2 * 4 * 128 * 128);
    float* fb3 = A((size_t)2 * 256 * 256);
    float* outp = (float*)d_out;

    // ---- Encoder levels 0-2 ----
    { dim3 g(64, 4); enc0_k<<<g, 256, 0, stream>>>(x1, x2, ew[0], eb[0], c2_0, p0); }
    enc_k<128, 4, 8, 2><<<512, 256, 0, stream>>>(p0, p0 + (size_t)2 * 4 * 128 * 128,
                                                 ew[1], eb[1], c2_1, p1);
    enc_k<64, 8, 16, 2><<<256, 256, 0, stream>>>(p1, p1 + (size_t)2 * 8 * 64 * 64,
                                                 ew[2], eb[2], c2_2, p2);

    // ---- bigprep: enc3 + attn levels 0-2 + fb1/fb2/fb3 ----
    bigprep_k<<<472, 256, 0, stream>>>(p0, p1, p2, pts, ew[3], eb[3], c2_3, p3,
                                       c2_0, c2_1, c2_2,
                                       dw[1], db[1], dw[2], db[2], dw[3], db[3],
                                       at0, at1, at2, fb1, fb2, fb3);

    // ---- prep2: attn3 + fb0 ----
    prep2_k<<<34, 256, 0, stream>>>(p3, c2_3, pts, dw[0], db[0], at3, fb0);

    // ---- Per-k decoder (parity 2x2 convs) ----
    dec0k_k<<<256, 256, 0, stream>>>(at3, fb0, dw[0], dec0);
    { dim3 g(32, 32); dec1k_k<<<g, 256, 0, stream>>>(dec0, at2, fb1, dw[1], dec1); }
    { dim3 g(64, 16); dechalf2_k<128, 8, 4, 17, 4, true><<<g, 256, 0, stream>>>(dec1, at1, fb2, dw[2], dec2); }
    { dim3 g(256, 16); dechalf2_k<256, 4, 1, 9, 5, false><<<g, 256, 0, stream>>>(dec2, at0, fb3, dw[3], outp); }
}